// Round 1
// baseline (18308.255 us; speedup 1.0000x reference)
//
#include <hip/hip_runtime.h>

// Problem constants (from reference)
#define HD 1024          // H
#define ID 2048          // INTER
#define NCHUNK 32        // S/CHUNK
#define CHUNKSZ 64
#define NB 8             // B
#define SEQ 2048         // S
#define ROWS 512         // B*CHUNK rows per chunk step
#define MTOT 524288.0f   // B*CHUNK*H (loss mean denominator)
#define EPSF 1e-6f

// ---------------------------------------------------------------------------
// helpers
// ---------------------------------------------------------------------------
__device__ __forceinline__ float sigmoidf_(float x) { return 1.f / (1.f + expf(-x)); }
__device__ __forceinline__ float siluf_(float x)    { return x / (1.f + expf(-x)); }

// blockDim.x == 256 assumed (4 waves)
__device__ __forceinline__ float block_reduce_sum(float v, float* s4) {
  #pragma unroll
  for (int off = 32; off > 0; off >>= 1) v += __shfl_down(v, off);
  int lane = threadIdx.x & 63, wid = threadIdx.x >> 6;
  if (lane == 0) s4[wid] = v;
  __syncthreads();
  float r = s4[0] + s4[1] + s4[2] + s4[3];
  __syncthreads();
  return r;
}

// ---------------------------------------------------------------------------
// Tiled fp32 GEMMs: 64x64 block tile, BK=16, 256 threads, 4x4 microtile
// ---------------------------------------------------------------------------
#define BM 64
#define BN 64
#define BK 16
#define PAD 4   // keep 16B alignment of [kk][4*t] slices

// C(M,N) = A(M,K) @ B(N,K)^T.  If chunk >= 0, A rows are remapped into x:
// row r -> x row ((r>>6)*SEQ + chunk*64 + (r&63)), lda = K.
__global__ __launch_bounds__(256) void gemm_nt(
    float* __restrict__ C, const float* __restrict__ A, const float* __restrict__ B,
    int M, int N, int K, int chunk)
{
  __shared__ float As[BK][BM + PAD];
  __shared__ float Bs[BK][BN + PAD];
  const int tid = threadIdx.x;
  const int tx = tid & 15, ty = tid >> 4;
  const int m0 = blockIdx.y * BM, n0 = blockIdx.x * BN;

  float acc[4][4] = {};
  for (int k0 = 0; k0 < K; k0 += BK) {
    #pragma unroll
    for (int it = 0; it < 4; ++it) {
      int idx = tid + it * 256;
      int kk = idx & 15, mm = idx >> 4;
      int row = m0 + mm;
      int arow = (chunk >= 0) ? ((row >> 6) * SEQ + chunk * CHUNKSZ + (row & 63)) : row;
      As[kk][mm] = A[(size_t)arow * K + k0 + kk];
    }
    #pragma unroll
    for (int it = 0; it < 4; ++it) {
      int idx = tid + it * 256;
      int kk = idx & 15, nn = idx >> 4;
      Bs[kk][nn] = B[(size_t)(n0 + nn) * K + k0 + kk];
    }
    __syncthreads();
    #pragma unroll
    for (int kk = 0; kk < BK; ++kk) {
      const float4 av = *(const float4*)&As[kk][ty * 4];
      const float4 bv = *(const float4*)&Bs[kk][tx * 4];
      acc[0][0] += av.x * bv.x; acc[0][1] += av.x * bv.y; acc[0][2] += av.x * bv.z; acc[0][3] += av.x * bv.w;
      acc[1][0] += av.y * bv.x; acc[1][1] += av.y * bv.y; acc[1][2] += av.y * bv.z; acc[1][3] += av.y * bv.w;
      acc[2][0] += av.z * bv.x; acc[2][1] += av.z * bv.y; acc[2][2] += av.z * bv.z; acc[2][3] += av.z * bv.w;
      acc[3][0] += av.w * bv.x; acc[3][1] += av.w * bv.y; acc[3][2] += av.w * bv.z; acc[3][3] += av.w * bv.w;
    }
    __syncthreads();
  }
  #pragma unroll
  for (int i = 0; i < 4; ++i) {
    int row = m0 + ty * 4 + i;
    #pragma unroll
    for (int j = 0; j < 4; ++j)
      C[(size_t)row * N + n0 + tx * 4 + j] = acc[i][j];
  }
}

// C(M,N) = A(M,K) @ B(K,N)   (B row-major K x N)
__global__ __launch_bounds__(256) void gemm_nn(
    float* __restrict__ C, const float* __restrict__ A, const float* __restrict__ B,
    int M, int N, int K)
{
  __shared__ float As[BK][BM + PAD];
  __shared__ float Bs[BK][BN + PAD];
  const int tid = threadIdx.x;
  const int tx = tid & 15, ty = tid >> 4;
  const int m0 = blockIdx.y * BM, n0 = blockIdx.x * BN;

  float acc[4][4] = {};
  for (int k0 = 0; k0 < K; k0 += BK) {
    #pragma unroll
    for (int it = 0; it < 4; ++it) {
      int idx = tid + it * 256;
      int kk = idx & 15, mm = idx >> 4;
      As[kk][mm] = A[(size_t)(m0 + mm) * K + k0 + kk];
    }
    #pragma unroll
    for (int it = 0; it < 4; ++it) {
      int idx = tid + it * 256;
      int nn = idx & 63, kk = idx >> 6;
      Bs[kk][nn] = B[(size_t)(k0 + kk) * N + n0 + nn];
    }
    __syncthreads();
    #pragma unroll
    for (int kk = 0; kk < BK; ++kk) {
      const float4 av = *(const float4*)&As[kk][ty * 4];
      const float4 bv = *(const float4*)&Bs[kk][tx * 4];
      acc[0][0] += av.x * bv.x; acc[0][1] += av.x * bv.y; acc[0][2] += av.x * bv.z; acc[0][3] += av.x * bv.w;
      acc[1][0] += av.y * bv.x; acc[1][1] += av.y * bv.y; acc[1][2] += av.y * bv.z; acc[1][3] += av.y * bv.w;
      acc[2][0] += av.z * bv.x; acc[2][1] += av.z * bv.y; acc[2][2] += av.z * bv.z; acc[2][3] += av.z * bv.w;
      acc[3][0] += av.w * bv.x; acc[3][1] += av.w * bv.y; acc[3][2] += av.w * bv.z; acc[3][3] += av.w * bv.w;
    }
    __syncthreads();
  }
  #pragma unroll
  for (int i = 0; i < 4; ++i) {
    int row = m0 + ty * 4 + i;
    #pragma unroll
    for (int j = 0; j < 4; ++j)
      C[(size_t)row * N + n0 + tx * 4 + j] = acc[i][j];
  }
}

// C(I,J) = A(Mred,I)^T @ B(Mred,J)  (reduction over leading dim Mred)
__global__ __launch_bounds__(256) void gemm_tn(
    float* __restrict__ C, const float* __restrict__ A, const float* __restrict__ B,
    int I, int J, int Mred)
{
  __shared__ float As[BK][BM + PAD];
  __shared__ float Bs[BK][BN + PAD];
  const int tid = threadIdx.x;
  const int tx = tid & 15, ty = tid >> 4;
  const int i0 = blockIdx.y * BM, j0 = blockIdx.x * BN;

  float acc[4][4] = {};
  for (int m0 = 0; m0 < Mred; m0 += BK) {
    #pragma unroll
    for (int it = 0; it < 4; ++it) {
      int idx = tid + it * 256;
      int ii = idx & 63, mm = idx >> 6;
      As[mm][ii] = A[(size_t)(m0 + mm) * I + i0 + ii];
    }
    #pragma unroll
    for (int it = 0; it < 4; ++it) {
      int idx = tid + it * 256;
      int jj = idx & 63, mm = idx >> 6;
      Bs[mm][jj] = B[(size_t)(m0 + mm) * J + j0 + jj];
    }
    __syncthreads();
    #pragma unroll
    for (int mm = 0; mm < BK; ++mm) {
      const float4 av = *(const float4*)&As[mm][ty * 4];
      const float4 bv = *(const float4*)&Bs[mm][tx * 4];
      acc[0][0] += av.x * bv.x; acc[0][1] += av.x * bv.y; acc[0][2] += av.x * bv.z; acc[0][3] += av.x * bv.w;
      acc[1][0] += av.y * bv.x; acc[1][1] += av.y * bv.y; acc[1][2] += av.y * bv.z; acc[1][3] += av.y * bv.w;
      acc[2][0] += av.z * bv.x; acc[2][1] += av.z * bv.y; acc[2][2] += av.z * bv.z; acc[2][3] += av.z * bv.w;
      acc[3][0] += av.w * bv.x; acc[3][1] += av.w * bv.y; acc[3][2] += av.w * bv.z; acc[3][3] += av.w * bv.w;
    }
    __syncthreads();
  }
  #pragma unroll
  for (int i = 0; i < 4; ++i) {
    int row = i0 + ty * 4 + i;
    #pragma unroll
    for (int j = 0; j < 4; ++j)
      C[(size_t)row * J + j0 + tx * 4 + j] = acc[i][j];
  }
}

// ---------------------------------------------------------------------------
// Small fused kernels
// ---------------------------------------------------------------------------

// per (b,chunk) dot products of the flattened 65536-elem chunk with aw/tw/ew
__global__ __launch_bounds__(256) void dots_kernel(
    const float* __restrict__ x, const float* __restrict__ aw,
    const float* __restrict__ tw, const float* __restrict__ ew,
    float* __restrict__ dA, float* __restrict__ dT, float* __restrict__ dE)
{
  int b = blockIdx.x >> 5, c = blockIdx.x & 31;
  const float* base = x + ((size_t)b * SEQ + (size_t)c * CHUNKSZ) * HD;
  float a = 0.f, t = 0.f, e = 0.f;
  for (int it = 0; it < 256; ++it) {
    int j = it * 256 + threadIdx.x;
    float xv = base[j];
    a += xv * aw[j]; t += xv * tw[j]; e += xv * ew[j];
  }
  __shared__ float s4[4];
  a = block_reduce_sum(a, s4);
  t = block_reduce_sum(t, s4);
  e = block_reduce_sum(e, s4);
  if (threadIdx.x == 0) { dA[blockIdx.x] = a; dT[blockIdx.x] = t; dE[blockIdx.x] = e; }
}

__global__ __launch_bounds__(256) void coeff_kernel(
    const float* __restrict__ dA, const float* __restrict__ dT, const float* __restrict__ dE,
    float* __restrict__ betaA, float* __restrict__ etaA, float* __restrict__ thetaA)
{
  int t = threadIdx.x;
  if (t < 256) thetaA[t] = sigmoidf_(dT[t]) * 0.01f;
  if (t < 32) {
    float sa = 0.f, se = 0.f;
    for (int b = 0; b < NB; ++b) { sa += dA[b * 32 + t]; se += dE[b * 32 + t]; }
    betaA[t] = 1.f - sigmoidf_(sa / 8.f);
    etaA[t]  = sigmoidf_(se / 8.f);
  }
}

// rmsnorm(silu(src_row)) * nw  -> dst_row   (one block per row, 1024 cols)
__global__ __launch_bounds__(256) void post_norm_silu(
    float* __restrict__ dst, const float* __restrict__ src, const float* __restrict__ nw)
{
  size_t off = (size_t)blockIdx.x * HD;
  float sv[4]; float ss = 0.f;
  #pragma unroll
  for (int i = 0; i < 4; ++i) {
    float z = src[off + i * 256 + threadIdx.x];
    float s = siluf_(z);
    sv[i] = s; ss += s * s;
  }
  __shared__ float s4[4];
  ss = block_reduce_sum(ss, s4);
  float rs = rsqrtf(ss / (float)HD + EPSF);
  #pragma unroll
  for (int i = 0; i < 4; ++i) {
    int j = i * 256 + threadIdx.x;
    dst[off + j] = sv[i] * rs * nw[j];
  }
}

__global__ __launch_bounds__(256) void silu_fwd(float* __restrict__ dst, const float* __restrict__ src, int n) {
  int i = blockIdx.x * 256 + threadIdx.x;
  if (i < n) dst[i] = siluf_(src[i]);
}

// dh *= silu'(z)
__global__ __launch_bounds__(256) void silu_bwd(float* __restrict__ dh, const float* __restrict__ z, int n) {
  int i = blockIdx.x * 256 + threadIdx.x;
  if (i < n) {
    float zz = z[i];
    float sg = 1.f / (1.f + expf(-zz));
    dh[i] = dh[i] * (sg * (1.f + zz * (1.f - sg)));
  }
}

// per-row: s, g = 2*th*(pred - v)/M, t = sum(g*ln*y), dY = s*g*ln - (s^3 t/H) y
__global__ __launch_bounds__(256) void loss_grad(
    const float* __restrict__ y, const float* __restrict__ kc, const float* __restrict__ vc,
    const float* __restrict__ ln, const float* __restrict__ thetaA, int c,
    float* __restrict__ g, float* __restrict__ dY, float* __restrict__ srow)
{
  int r = blockIdx.x;
  size_t off = (size_t)r * HD;
  float th = thetaA[(r >> 6) * 32 + c];
  float yv[4], lnv[4];
  float ss = 0.f;
  #pragma unroll
  for (int i = 0; i < 4; ++i) {
    int j = i * 256 + threadIdx.x;
    yv[i] = y[off + j];
    lnv[i] = ln[j];
    ss += yv[i] * yv[i];
  }
  __shared__ float s4[4];
  ss = block_reduce_sum(ss, s4);
  float s = rsqrtf(ss / (float)HD + EPSF);
  float coef = 2.f * th / MTOT;
  float gv[4]; float t = 0.f;
  #pragma unroll
  for (int i = 0; i < 4; ++i) {
    int j = i * 256 + threadIdx.x;
    float pred = kc[off + j] + yv[i] * s * lnv[i];
    float gg = coef * (pred - vc[off + j]);
    gv[i] = gg;
    g[off + j] = gg;
    t += gg * lnv[i] * yv[i];
  }
  t = block_reduce_sum(t, s4);
  float c3 = s * s * s * t * (1.f / (float)HD);
  #pragma unroll
  for (int i = 0; i < 4; ++i) {
    int j = i * 256 + threadIdx.x;
    dY[off + j] = s * gv[i] * lnv[i] - c3 * yv[i];
  }
  if (threadIdx.x == 0) srow[r] = s;
}

// Gln[j] += sum over 16 rows of g*y*s   (grid: (4, 32))
__global__ __launch_bounds__(256) void gln_kernel(
    const float* __restrict__ g, const float* __restrict__ y,
    const float* __restrict__ srow, float* __restrict__ Gln)
{
  int j = blockIdx.x * 256 + threadIdx.x;
  int r0 = blockIdx.y * 16;
  float acc = 0.f;
  #pragma unroll
  for (int rr = 0; rr < 16; ++rr) {
    int r = r0 + rr;
    size_t o = (size_t)r * HD + j;
    acc += g[o] * y[o] * srow[r];
  }
  atomicAdd(&Gln[j], acc);
}

__global__ __launch_bounds__(256) void norm_reduce(
    const float* __restrict__ g0, const float* __restrict__ g1,
    const float* __restrict__ gl, float* __restrict__ nsq)
{
  float acc = 0.f;
  int stride = gridDim.x * 256;
  int start = blockIdx.x * 256 + threadIdx.x;
  for (int i = start; i < ID * HD; i += stride) { float v = g0[i]; acc += v * v; }
  for (int i = start; i < HD * ID; i += stride) { float v = g1[i]; acc += v * v; }
  for (int i = start; i < HD; i += stride)      { float v = gl[i]; acc += v * v; }
  __shared__ float s4[4];
  acc = block_reduce_sum(acc, s4);
  if (threadIdx.x == 0) atomicAdd(nsq, acc);
}

__global__ __launch_bounds__(256) void update_kernel(
    float* __restrict__ mw0, float* __restrict__ mw1, float* __restrict__ mln,
    float* __restrict__ sw0, float* __restrict__ sw1, float* __restrict__ sln,
    const float* __restrict__ g0, const float* __restrict__ g1, const float* __restrict__ gl,
    const float* __restrict__ etaA, const float* __restrict__ betaA, int c,
    const float* __restrict__ nsq)
{
  int idx = blockIdx.x * 256 + threadIdx.x;
  float total = sqrtf(*nsq);
  float clip = fminf(1.0f / (total + 1e-6f), 1.0f);
  float eta = etaA[c], beta = betaA[c];
  float *m, *s; const float* g; int i;
  if (idx < ID * HD)            { m = mw0; s = sw0; g = g0; i = idx; }
  else if (idx < 2 * ID * HD)   { m = mw1; s = sw1; g = g1; i = idx - ID * HD; }
  else                          { m = mln; s = sln; g = gl; i = idx - 2 * ID * HD; }
  float ns = eta * s[i] - clip * g[i];
  s[i] = ns;
  m[i] = beta * m[i] + ns;
}

// out = qb + rmsnorm(y2, ln)   (one block per row)
__global__ __launch_bounds__(256) void final_out_kernel(
    float* __restrict__ out, const float* __restrict__ qb,
    const float* __restrict__ y2, const float* __restrict__ ln)
{
  size_t off = (size_t)blockIdx.x * HD;
  float yv[4]; float ss = 0.f;
  #pragma unroll
  for (int i = 0; i < 4; ++i) {
    yv[i] = y2[off + i * 256 + threadIdx.x];
    ss += yv[i] * yv[i];
  }
  __shared__ float s4[4];
  ss = block_reduce_sum(ss, s4);
  float s = rsqrtf(ss / (float)HD + EPSF);
  #pragma unroll
  for (int i = 0; i < 4; ++i) {
    int j = i * 256 + threadIdx.x;
    out[off + j] = qb[off + j] + yv[i] * s * ln[j];
  }
}

// ---------------------------------------------------------------------------
// launch
// ---------------------------------------------------------------------------
extern "C" void kernel_launch(void* const* d_in, const int* in_sizes, int n_in,
                              void* d_out, int out_size, void* d_ws, size_t ws_size,
                              hipStream_t stream) {
  const float* x   = (const float*)d_in[0];
  const float* wq  = (const float*)d_in[1];
  const float* wk  = (const float*)d_in[2];
  const float* wv  = (const float*)d_in[3];
  const float* qn  = (const float*)d_in[4];
  const float* kn  = (const float*)d_in[5];
  const float* aw  = (const float*)d_in[6];
  const float* tw  = (const float*)d_in[7];
  const float* ew  = (const float*)d_in[8];
  const float* w0i = (const float*)d_in[9];
  const float* w1i = (const float*)d_in[10];
  const float* lni = (const float*)d_in[11];
  float* out = (float*)d_out;

  // workspace carve-up (floats)
  float* p = (float*)d_ws;
  auto alloc = [&](size_t n) { float* r = p; p += n; return r; };
  float* memW0  = alloc((size_t)ID * HD);   // 2097152
  float* memW1  = alloc((size_t)HD * ID);
  float* memLn  = alloc(HD);
  float* surpW0 = alloc((size_t)ID * HD);   // surp* must stay contiguous (one memset)
  float* surpW1 = alloc((size_t)HD * ID);
  float* surpLn = alloc(HD);
  float* Gw0    = alloc((size_t)ID * HD);
  float* Gw1    = alloc((size_t)HD * ID);
  float* Gln    = alloc(HD);
  float* kcb    = alloc((size_t)ROWS * HD);
  float* vcb    = alloc((size_t)ROWS * HD);
  float* zkv    = alloc((size_t)ROWS * HD);
  float* zfw    = alloc((size_t)ROWS * ID);
  float* hfw    = alloc((size_t)ROWS * ID);
  float* ybuf   = alloc((size_t)ROWS * HD);
  float* gbuf   = alloc((size_t)ROWS * HD);
  float* dYb    = alloc((size_t)ROWS * HD);
  float* dHb    = alloc((size_t)ROWS * ID);
  float* srow   = alloc(ROWS);
  float* dotA   = alloc(256);
  float* dotT   = alloc(256);
  float* dotE   = alloc(256);
  float* betaA  = alloc(32);
  float* etaA   = alloc(32);
  float* thetaA = alloc(256);
  float* nsq    = alloc(1);
  size_t needed = (size_t)(p - (float*)d_ws) * sizeof(float);
  if (needed > ws_size) return;  // fail loudly (output stays wrong) rather than corrupt

  // init state
  hipMemcpyAsync(memW0, w0i, (size_t)ID * HD * 4, hipMemcpyDeviceToDevice, stream);
  hipMemcpyAsync(memW1, w1i, (size_t)HD * ID * 4, hipMemcpyDeviceToDevice, stream);
  hipMemcpyAsync(memLn, lni, (size_t)HD * 4, hipMemcpyDeviceToDevice, stream);
  hipMemsetAsync(surpW0, 0, ((size_t)ID * HD * 2 + HD) * 4, stream);

  // adaptive per-chunk coefficients
  dots_kernel<<<256, 256, 0, stream>>>(x, aw, tw, ew, dotA, dotT, dotE);
  coeff_kernel<<<1, 256, 0, stream>>>(dotA, dotT, dotE, betaA, etaA, thetaA);

  // sequential scan over chunks
  for (int c = 0; c < NCHUNK; ++c) {
    // k_c = rmsnorm(silu(xc @ wk^T), kn); v_c = silu(xc @ wv^T)
    gemm_nt<<<dim3(HD / BN, ROWS / BM), 256, 0, stream>>>(zkv, x, wk, ROWS, HD, HD, c);
    post_norm_silu<<<ROWS, 256, 0, stream>>>(kcb, zkv, kn);
    gemm_nt<<<dim3(HD / BN, ROWS / BM), 256, 0, stream>>>(zkv, x, wv, ROWS, HD, HD, c);
    silu_fwd<<<(ROWS * HD) / 256, 256, 0, stream>>>(vcb, zkv, ROWS * HD);
    // forward through memory MLP
    gemm_nt<<<dim3(ID / BN, ROWS / BM), 256, 0, stream>>>(zfw, kcb, memW0, ROWS, ID, HD, -1);
    silu_fwd<<<(ROWS * ID) / 256, 256, 0, stream>>>(hfw, zfw, ROWS * ID);
    gemm_nt<<<dim3(HD / BN, ROWS / BM), 256, 0, stream>>>(ybuf, hfw, memW1, ROWS, HD, ID, -1);
    // loss gradient wrt y (+ g for Gln)
    loss_grad<<<ROWS, 256, 0, stream>>>(ybuf, kcb, vcb, memLn, thetaA, c, gbuf, dYb, srow);
    hipMemsetAsync(Gln, 0, HD * 4, stream);
    gln_kernel<<<dim3(4, 32), 256, 0, stream>>>(gbuf, ybuf, srow, Gln);
    // weight grads
    gemm_tn<<<dim3(ID / BN, HD / BM), 256, 0, stream>>>(Gw1, dYb, hfw, HD, ID, ROWS);
    gemm_nn<<<dim3(ID / BN, ROWS / BM), 256, 0, stream>>>(dHb, dYb, memW1, ROWS, ID, HD);
    silu_bwd<<<(ROWS * ID) / 256, 256, 0, stream>>>(dHb, zfw, ROWS * ID);
    gemm_tn<<<dim3(HD / BN, ID / BM), 256, 0, stream>>>(Gw0, dHb, kcb, ID, HD, ROWS);
    // clip + update
    hipMemsetAsync(nsq, 0, 4, stream);
    norm_reduce<<<1024, 256, 0, stream>>>(Gw0, Gw1, Gln, nsq);
    update_kernel<<<(2 * ID * HD + HD) / 256, 256, 0, stream>>>(
        memW0, memW1, memLn, surpW0, surpW1, surpLn, Gw0, Gw1, Gln, etaA, betaA, c, nsq);
  }

  // final retrieval: out = mem_fwd(mem_f, q), q = rmsnorm(silu(x @ wq^T), qn)
  // row-blocked by 1024 rows; reuse scan buffers (free after the scan)
  float* zq = zfw;   // 1024*1024
  float* qb = hfw;   // 1024*1024
  float* z2 = Gw0;   // 1024*2048
  float* y2 = Gw1;   // 1024*1024
  const int RB = 1024;
  for (int blk = 0; blk < (NB * SEQ) / RB; ++blk) {
    const float* xb = x + (size_t)blk * RB * HD;
    gemm_nt<<<dim3(HD / BN, RB / BM), 256, 0, stream>>>(zq, xb, wq, RB, HD, HD, -1);
    post_norm_silu<<<RB, 256, 0, stream>>>(qb, zq, qn);
    gemm_nt<<<dim3(ID / BN, RB / BM), 256, 0, stream>>>(z2, qb, memW0, RB, ID, HD, -1);
    silu_fwd<<<(RB * ID) / 256, 256, 0, stream>>>(z2, z2, RB * ID);
    gemm_nt<<<dim3(HD / BN, RB / BM), 256, 0, stream>>>(y2, z2, memW1, RB, HD, ID, -1);
    final_out_kernel<<<RB, 256, 0, stream>>>(out + (size_t)blk * RB * HD, qb, y2, memLn);
  }
}

// Round 2
// 7335.249 us; speedup vs baseline: 2.4959x; 2.4959x over previous
//
#include <hip/hip_runtime.h>

#define HD 1024
#define ID 2048
#define NCHUNK 32
#define CHUNKSZ 64
#define NB 8
#define SEQ 2048
#define ROWS 512
#define MTOT 524288.0f
#define EPSF 1e-6f

typedef unsigned short u16;
typedef unsigned int u32;
typedef short bf16x8 __attribute__((ext_vector_type(8)));
typedef float f32x4 __attribute__((ext_vector_type(4)));

__device__ __forceinline__ float sigmoidf_(float x) { return 1.f / (1.f + expf(-x)); }
__device__ __forceinline__ float siluf_(float x)    { return x / (1.f + expf(-x)); }
__device__ __forceinline__ float silu_d_(float z)   { float sg = sigmoidf_(z); return sg * (1.f + z * (1.f - sg)); }

// fp32 -> bf16 round-to-nearest-even
__device__ __forceinline__ u16 f2b(float f) {
  union { float f; u32 u; } v; v.f = f;
  return (u16)((v.u + 0x7fffu + ((v.u >> 16) & 1u)) >> 16);
}
__device__ __forceinline__ u32 pack2(float a, float b) { return (u32)f2b(a) | ((u32)f2b(b) << 16); }

// block 256 reduce
__device__ __forceinline__ float block_reduce_sum(float v, float* s4) {
  #pragma unroll
  for (int off = 32; off > 0; off >>= 1) v += __shfl_down(v, off);
  int lane = threadIdx.x & 63, wid = threadIdx.x >> 6;
  if (lane == 0) s4[wid] = v;
  __syncthreads();
  float r = s4[0] + s4[1] + s4[2] + s4[3];
  __syncthreads();
  return r;
}

// ---------------------------------------------------------------------------
// MFMA NT GEMMs: C(MxN) fp32 = A(MxK) @ B(NxK)^T, A/B bf16 (u16 storage)
// 16x16x32 bf16 MFMA. LDS row stride 40 elems (80B: 16B-aligned, 2-way-conflict only).
// ---------------------------------------------------------------------------
__global__ __launch_bounds__(256) void mfma_nt_128(
    float* __restrict__ C, const u16* __restrict__ A, const u16* __restrict__ B,
    int M, int N, int K)
{
  __shared__ __align__(16) u16 As[128 * 40];
  __shared__ __align__(16) u16 Bs[128 * 40];
  const int tid = threadIdx.x;
  const int lane = tid & 63, wave = tid >> 6;
  const int wr = wave >> 1, wc = wave & 1;
  const int l15 = lane & 15, q = lane >> 4;
  const int m0 = blockIdx.y * 128, n0 = blockIdx.x * 128;

  f32x4 acc[4][4] = {};
  for (int k0 = 0; k0 < K; k0 += 32) {
    #pragma unroll
    for (int it = 0; it < 2; ++it) {
      int cid = tid + it * 256;           // 512 chunks of 8 bf16
      int row = cid >> 2, c8 = (cid & 3) * 8;
      *(uint4*)&As[row * 40 + c8] = *(const uint4*)&A[(size_t)(m0 + row) * K + k0 + c8];
      *(uint4*)&Bs[row * 40 + c8] = *(const uint4*)&B[(size_t)(n0 + row) * K + k0 + c8];
    }
    __syncthreads();
    bf16x8 af[4], bg[4];
    #pragma unroll
    for (int i = 0; i < 4; ++i) af[i] = *(const bf16x8*)&As[(wr * 64 + i * 16 + l15) * 40 + q * 8];
    #pragma unroll
    for (int j = 0; j < 4; ++j) bg[j] = *(const bf16x8*)&Bs[(wc * 64 + j * 16 + l15) * 40 + q * 8];
    #pragma unroll
    for (int i = 0; i < 4; ++i)
      #pragma unroll
      for (int j = 0; j < 4; ++j)
        acc[i][j] = __builtin_amdgcn_mfma_f32_16x16x32_bf16(af[i], bg[j], acc[i][j], 0, 0, 0);
    __syncthreads();
  }
  #pragma unroll
  for (int i = 0; i < 4; ++i) {
    int r = m0 + wr * 64 + i * 16 + q * 4;
    #pragma unroll
    for (int j = 0; j < 4; ++j) {
      float* cp = &C[(size_t)r * N + n0 + wc * 64 + j * 16 + l15];
      #pragma unroll
      for (int t = 0; t < 4; ++t) cp[(size_t)t * N] = acc[i][j][t];
    }
  }
}

__global__ __launch_bounds__(256) void mfma_nt_64(
    float* __restrict__ C, const u16* __restrict__ A, const u16* __restrict__ B,
    int M, int N, int K)
{
  __shared__ __align__(16) u16 As[64 * 40];
  __shared__ __align__(16) u16 Bs[64 * 40];
  const int tid = threadIdx.x;
  const int lane = tid & 63, wave = tid >> 6;
  const int wr = wave >> 1, wc = wave & 1;
  const int l15 = lane & 15, q = lane >> 4;
  const int m0 = blockIdx.y * 64, n0 = blockIdx.x * 64;

  f32x4 acc[2][2] = {};
  for (int k0 = 0; k0 < K; k0 += 32) {
    {
      int row = tid >> 2, c8 = (tid & 3) * 8;  // 256 chunks
      *(uint4*)&As[row * 40 + c8] = *(const uint4*)&A[(size_t)(m0 + row) * K + k0 + c8];
      *(uint4*)&Bs[row * 40 + c8] = *(const uint4*)&B[(size_t)(n0 + row) * K + k0 + c8];
    }
    __syncthreads();
    bf16x8 af[2], bg[2];
    #pragma unroll
    for (int i = 0; i < 2; ++i) af[i] = *(const bf16x8*)&As[(wr * 32 + i * 16 + l15) * 40 + q * 8];
    #pragma unroll
    for (int j = 0; j < 2; ++j) bg[j] = *(const bf16x8*)&Bs[(wc * 32 + j * 16 + l15) * 40 + q * 8];
    #pragma unroll
    for (int i = 0; i < 2; ++i)
      #pragma unroll
      for (int j = 0; j < 2; ++j)
        acc[i][j] = __builtin_amdgcn_mfma_f32_16x16x32_bf16(af[i], bg[j], acc[i][j], 0, 0, 0);
    __syncthreads();
  }
  #pragma unroll
  for (int i = 0; i < 2; ++i) {
    int r = m0 + wr * 32 + i * 16 + q * 4;
    #pragma unroll
    for (int j = 0; j < 2; ++j) {
      float* cp = &C[(size_t)r * N + n0 + wc * 32 + j * 16 + l15];
      #pragma unroll
      for (int t = 0; t < 4; ++t) cp[(size_t)t * N] = acc[i][j][t];
    }
  }
}

// ---------------------------------------------------------------------------
// conversions & transposes
// ---------------------------------------------------------------------------
__global__ __launch_bounds__(256) void conv_f2b(u16* __restrict__ dst, const float* __restrict__ src, int n) {
  int i = (blockIdx.x * 256 + threadIdx.x) * 4;
  if (i < n) {
    float4 v = *(const float4*)&src[i];
    uint2 o; o.x = pack2(v.x, v.y); o.y = pack2(v.z, v.w);
    *(uint2*)&dst[i] = o;
  }
}

// chunk c of x (rows (b, c*64+r)) -> xc_bf (512 x 1024)
__global__ __launch_bounds__(256) void conv_chunk(u16* __restrict__ dst, const float* __restrict__ x, int c) {
  int r = blockIdx.x;
  int arow = (r >> 6) * SEQ + c * CHUNKSZ + (r & 63);
  const float* s = x + (size_t)arow * HD;
  u16* d = dst + (size_t)r * HD;
  int j = threadIdx.x * 4;
  float4 v = *(const float4*)&s[j];
  uint2 o; o.x = pack2(v.x, v.y); o.y = pack2(v.z, v.w);
  *(uint2*)&d[j] = o;
}

// dst(CxR) bf16 = transpose(src(RxC) fp32)
__global__ __launch_bounds__(256) void trans_f2b(u16* __restrict__ dst, const float* __restrict__ src, int R, int C) {
  __shared__ u16 t[64][66];
  int r0 = blockIdx.y * 64, c0 = blockIdx.x * 64;
  #pragma unroll
  for (int it = 0; it < 16; ++it) {
    int idx = threadIdx.x + it * 256;
    int r = idx >> 6, c = idx & 63;
    t[c][r] = f2b(src[(size_t)(r0 + r) * C + c0 + c]);
  }
  __syncthreads();
  #pragma unroll
  for (int it = 0; it < 16; ++it) {
    int idx = threadIdx.x + it * 256;
    int r = idx >> 6, c = idx & 63;
    dst[(size_t)(c0 + r) * R + r0 + c] = t[r][c];
  }
}

// dst(CxR) bf16 = transpose(src(RxC) bf16)
__global__ __launch_bounds__(256) void trans_b2b(u16* __restrict__ dst, const u16* __restrict__ src, int R, int C) {
  __shared__ u16 t[64][66];
  int r0 = blockIdx.y * 64, c0 = blockIdx.x * 64;
  #pragma unroll
  for (int it = 0; it < 16; ++it) {
    int idx = threadIdx.x + it * 256;
    int r = idx >> 6, c = idx & 63;
    t[c][r] = src[(size_t)(r0 + r) * C + c0 + c];
  }
  __syncthreads();
  #pragma unroll
  for (int it = 0; it < 16; ++it) {
    int idx = threadIdx.x + it * 256;
    int r = idx >> 6, c = idx & 63;
    dst[(size_t)(c0 + r) * R + r0 + c] = t[r][c];
  }
}

// dst(CxR) bf16 = transpose(dh(RxC) * silu'(z(RxC)))
__global__ __launch_bounds__(256) void trans_silu_bwd(u16* __restrict__ dst, const float* __restrict__ dh,
                                                      const float* __restrict__ z, int R, int C) {
  __shared__ u16 t[64][66];
  int r0 = blockIdx.y * 64, c0 = blockIdx.x * 64;
  #pragma unroll
  for (int it = 0; it < 16; ++it) {
    int idx = threadIdx.x + it * 256;
    int r = idx >> 6, c = idx & 63;
    size_t o = (size_t)(r0 + r) * C + c0 + c;
    t[c][r] = f2b(dh[o] * silu_d_(z[o]));
  }
  __syncthreads();
  #pragma unroll
  for (int it = 0; it < 16; ++it) {
    int idx = threadIdx.x + it * 256;
    int r = idx >> 6, c = idx & 63;
    dst[(size_t)(c0 + r) * R + r0 + c] = t[r][c];
  }
}

// ---------------------------------------------------------------------------
// fused small kernels
// ---------------------------------------------------------------------------
__global__ __launch_bounds__(256) void dots_kernel(
    const float* __restrict__ x, const float* __restrict__ aw,
    const float* __restrict__ tw, const float* __restrict__ ew,
    float* __restrict__ dA, float* __restrict__ dT, float* __restrict__ dE)
{
  int b = blockIdx.x >> 5, c = blockIdx.x & 31;
  const float* base = x + ((size_t)b * SEQ + (size_t)c * CHUNKSZ) * HD;
  float a = 0.f, t = 0.f, e = 0.f;
  for (int it = 0; it < 256; ++it) {
    int j = it * 256 + threadIdx.x;
    float xv = base[j];
    a += xv * aw[j]; t += xv * tw[j]; e += xv * ew[j];
  }
  __shared__ float s4[4];
  a = block_reduce_sum(a, s4);
  t = block_reduce_sum(t, s4);
  e = block_reduce_sum(e, s4);
  if (threadIdx.x == 0) { dA[blockIdx.x] = a; dT[blockIdx.x] = t; dE[blockIdx.x] = e; }
}

__global__ __launch_bounds__(256) void coeff_kernel(
    const float* __restrict__ dA, const float* __restrict__ dT, const float* __restrict__ dE,
    float* __restrict__ betaA, float* __restrict__ etaA, float* __restrict__ thetaA)
{
  int t = threadIdx.x;
  if (t < 256) thetaA[t] = sigmoidf_(dT[t]) * 0.01f;
  if (t < 32) {
    float sa = 0.f, se = 0.f;
    for (int b = 0; b < NB; ++b) { sa += dA[b * 32 + t]; se += dE[b * 32 + t]; }
    betaA[t] = 1.f - sigmoidf_(sa / 8.f);
    etaA[t]  = sigmoidf_(se / 8.f);
  }
}

// dst = rmsnorm(silu(src)) * nw, fp32 + bf16 outs (one block per row)
__global__ __launch_bounds__(256) void post_norm_silu(
    float* __restrict__ dst, u16* __restrict__ dstb,
    const float* __restrict__ src, const float* __restrict__ nw)
{
  size_t off = (size_t)blockIdx.x * HD;
  float sv[4]; float ss = 0.f;
  #pragma unroll
  for (int i = 0; i < 4; ++i) {
    float z = src[off + i * 256 + threadIdx.x];
    float s = siluf_(z);
    sv[i] = s; ss += s * s;
  }
  __shared__ float s4[4];
  ss = block_reduce_sum(ss, s4);
  float rs = rsqrtf(ss / (float)HD + EPSF);
  #pragma unroll
  for (int i = 0; i < 4; ++i) {
    int j = i * 256 + threadIdx.x;
    float o = sv[i] * rs * nw[j];
    dst[off + j] = o;
    dstb[off + j] = f2b(o);
  }
}

// bf16(silu(src)), 4 elems/thread
__global__ __launch_bounds__(256) void silu_bf(u16* __restrict__ dst, const float* __restrict__ src, int n) {
  int i = (blockIdx.x * 256 + threadIdx.x) * 4;
  if (i < n) {
    float4 v = *(const float4*)&src[i];
    uint2 o; o.x = pack2(siluf_(v.x), siluf_(v.y)); o.y = pack2(siluf_(v.z), siluf_(v.w));
    *(uint2*)&dst[i] = o;
  }
}

// per-row loss grad; v = silu(zv_raw) computed inline
__global__ __launch_bounds__(256) void loss_grad(
    const float* __restrict__ y, const float* __restrict__ kc, const float* __restrict__ zvraw,
    const float* __restrict__ ln, const float* __restrict__ thetaA, int c,
    float* __restrict__ g, float* __restrict__ dY, u16* __restrict__ dYbf, float* __restrict__ srow)
{
  int r = blockIdx.x;
  size_t off = (size_t)r * HD;
  float th = thetaA[(r >> 6) * 32 + c];
  float yv[4], lnv[4];
  float ss = 0.f;
  #pragma unroll
  for (int i = 0; i < 4; ++i) {
    int j = i * 256 + threadIdx.x;
    yv[i] = y[off + j];
    lnv[i] = ln[j];
    ss += yv[i] * yv[i];
  }
  __shared__ float s4[4];
  ss = block_reduce_sum(ss, s4);
  float s = rsqrtf(ss / (float)HD + EPSF);
  float coef = 2.f * th / MTOT;
  float gv[4]; float t = 0.f;
  #pragma unroll
  for (int i = 0; i < 4; ++i) {
    int j = i * 256 + threadIdx.x;
    float pred = kc[off + j] + yv[i] * s * lnv[i];
    float vv = siluf_(zvraw[off + j]);
    float gg = coef * (pred - vv);
    gv[i] = gg;
    g[off + j] = gg;
    t += gg * lnv[i] * yv[i];
  }
  t = block_reduce_sum(t, s4);
  float c3 = s * s * s * t * (1.f / (float)HD);
  #pragma unroll
  for (int i = 0; i < 4; ++i) {
    int j = i * 256 + threadIdx.x;
    float d = s * gv[i] * lnv[i] - c3 * yv[i];
    dY[off + j] = d;
    dYbf[off + j] = f2b(d);
  }
  if (threadIdx.x == 0) srow[r] = s;
}

// Gln[j] += sum over 64 rows of g*y*s (grid (4, 8), atomic)
__global__ __launch_bounds__(256) void gln_kernel(
    const float* __restrict__ g, const float* __restrict__ y,
    const float* __restrict__ srow, float* __restrict__ Gln)
{
  int j = blockIdx.x * 256 + threadIdx.x;
  int r0 = blockIdx.y * 64;
  float acc = 0.f;
  #pragma unroll 4
  for (int rr = 0; rr < 64; ++rr) {
    int r = r0 + rr;
    size_t o = (size_t)r * HD + j;
    acc += g[o] * y[o] * srow[r];
  }
  atomicAdd(&Gln[j], acc);
}

__global__ __launch_bounds__(256) void norm_reduce(
    const float* __restrict__ g0, const float* __restrict__ g1,
    const float* __restrict__ gl, float* __restrict__ nsq)
{
  float acc = 0.f;
  int stride = gridDim.x * 256;
  int start = blockIdx.x * 256 + threadIdx.x;
  for (int i = start; i < ID * HD; i += stride) { float v = g0[i]; acc += v * v; }
  for (int i = start; i < HD * ID; i += stride) { float v = g1[i]; acc += v * v; }
  for (int i = start; i < HD; i += stride)      { float v = gl[i]; acc += v * v; }
  __shared__ float s4[4];
  acc = block_reduce_sum(acc, s4);
  if (threadIdx.x == 0) atomicAdd(nsq, acc);
}

__global__ __launch_bounds__(256) void update_kernel(
    float* __restrict__ mw0, float* __restrict__ mw1, float* __restrict__ mln,
    float* __restrict__ sw0, float* __restrict__ sw1, float* __restrict__ sln,
    const float* __restrict__ g0, const float* __restrict__ g1, const float* __restrict__ gl,
    u16* __restrict__ w0b, u16* __restrict__ w1b,
    const float* __restrict__ etaA, const float* __restrict__ betaA, int c,
    const float* __restrict__ nsq)
{
  int idx = blockIdx.x * 256 + threadIdx.x;
  float total = sqrtf(*nsq);
  float clip = fminf(1.0f / (total + 1e-6f), 1.0f);
  float eta = etaA[c], beta = betaA[c];
  if (idx < ID * HD) {
    float ns = eta * sw0[idx] - clip * g0[idx];
    sw0[idx] = ns;
    float m = beta * mw0[idx] + ns;
    mw0[idx] = m;
    w0b[idx] = f2b(m);
  } else if (idx < 2 * ID * HD) {
    int i = idx - ID * HD;
    float ns = eta * sw1[i] - clip * g1[i];
    sw1[i] = ns;
    float m = beta * mw1[i] + ns;
    mw1[i] = m;
    w1b[i] = f2b(m);
  } else {
    int i = idx - 2 * ID * HD;
    float ns = eta * sln[i] - clip * gl[i];
    sln[i] = ns;
    mln[i] = beta * mln[i] + ns;
  }
}

// out = qb + rmsnorm(y2)*ln (one block per row)
__global__ __launch_bounds__(256) void final_out_kernel(
    float* __restrict__ out, const float* __restrict__ qb,
    const float* __restrict__ y2, const float* __restrict__ ln)
{
  size_t off = (size_t)blockIdx.x * HD;
  float yv[4]; float ss = 0.f;
  #pragma unroll
  for (int i = 0; i < 4; ++i) {
    yv[i] = y2[off + i * 256 + threadIdx.x];
    ss += yv[i] * yv[i];
  }
  __shared__ float s4[4];
  ss = block_reduce_sum(ss, s4);
  float s = rsqrtf(ss / (float)HD + EPSF);
  #pragma unroll
  for (int i = 0; i < 4; ++i) {
    int j = i * 256 + threadIdx.x;
    out[off + j] = qb[off + j] + yv[i] * s * ln[j];
  }
}

// ---------------------------------------------------------------------------
// launch
// ---------------------------------------------------------------------------
extern "C" void kernel_launch(void* const* d_in, const int* in_sizes, int n_in,
                              void* d_out, int out_size, void* d_ws, size_t ws_size,
                              hipStream_t stream) {
  const float* x   = (const float*)d_in[0];
  const float* wq  = (const float*)d_in[1];
  const float* wk  = (const float*)d_in[2];
  const float* wv  = (const float*)d_in[3];
  const float* qn  = (const float*)d_in[4];
  const float* kn  = (const float*)d_in[5];
  const float* aw  = (const float*)d_in[6];
  const float* tw  = (const float*)d_in[7];
  const float* ew  = (const float*)d_in[8];
  const float* w0i = (const float*)d_in[9];
  const float* w1i = (const float*)d_in[10];
  const float* lni = (const float*)d_in[11];
  float* out = (float*)d_out;

  // fp32 region
  float* p = (float*)d_ws;
  auto alloc = [&](size_t n) { n = (n + 63) & ~(size_t)63; float* r = p; p += n; return r; };
  float* memW0  = alloc((size_t)ID * HD);
  float* memW1  = alloc((size_t)HD * ID);
  float* memLn  = alloc(HD);
  float* surpW0 = alloc((size_t)ID * HD);
  float* surpW1 = alloc((size_t)HD * ID);
  float* surpLn = alloc(HD);
  float* Gw0    = alloc((size_t)ID * HD);   // Gw0+Gw1 contiguous: reused as z2 in retrieval
  float* Gw1    = alloc((size_t)HD * ID);
  float* Gln    = alloc(HD);
  float* zkv    = alloc((size_t)ROWS * HD);
  float* zfw    = alloc((size_t)ROWS * ID);
  float* kcb    = alloc((size_t)ROWS * HD);
  float* ybuf   = alloc((size_t)ROWS * HD);
  float* gbuf   = alloc((size_t)ROWS * HD); // gbuf+dYb contiguous: reused as qb_bf
  float* dYb    = alloc((size_t)ROWS * HD);
  float* dHb    = alloc((size_t)ROWS * ID); // reused as xq_bf
  float* srow   = alloc(ROWS);
  float* dotA   = alloc(256);
  float* dotT   = alloc(256);
  float* dotE   = alloc(256);
  float* betaA  = alloc(64);
  float* etaA   = alloc(64);
  float* thetaA = alloc(256);
  float* nsq    = alloc(64);

  // bf16 region
  u16* bp = (u16*)p;
  auto balloc = [&](size_t n) { n = (n + 63) & ~(size_t)63; u16* r = bp; bp += n; return r; };
  u16* xc_bf   = balloc((size_t)ROWS * HD);
  u16* wq_bf   = balloc((size_t)HD * HD);
  u16* wk_bf   = balloc((size_t)HD * HD);
  u16* wv_bf   = balloc((size_t)HD * HD);
  u16* W0_bf   = balloc((size_t)ID * HD);
  u16* W1_bf   = balloc((size_t)HD * ID);
  u16* W1t_bf  = balloc((size_t)ID * HD);
  u16* kcb_bf  = balloc((size_t)ROWS * HD);
  u16* kcbt_bf = balloc((size_t)HD * ROWS);
  u16* hfw_bf  = balloc((size_t)ROWS * ID);
  u16* hfwt_bf = balloc((size_t)ID * ROWS);
  u16* dY_bf   = balloc((size_t)ROWS * HD);
  u16* dYt_bf  = balloc((size_t)HD * ROWS);
  u16* dHt_bf  = balloc((size_t)ID * ROWS);
  size_t needed = (size_t)((char*)bp - (char*)d_ws);
  if (needed > ws_size) return;

  // ---- setup ----
  hipMemcpyAsync(memW0, w0i, (size_t)ID * HD * 4, hipMemcpyDeviceToDevice, stream);
  hipMemcpyAsync(memW1, w1i, (size_t)HD * ID * 4, hipMemcpyDeviceToDevice, stream);
  hipMemcpyAsync(memLn, lni, (size_t)HD * 4, hipMemcpyDeviceToDevice, stream);
  hipMemsetAsync(surpW0, 0, ((size_t)ID * HD * 2 + HD + 64) * 4, stream);
  conv_f2b<<<(HD * HD) / 1024, 256, 0, stream>>>(wq_bf, wq, HD * HD);
  conv_f2b<<<(HD * HD) / 1024, 256, 0, stream>>>(wk_bf, wk, HD * HD);
  conv_f2b<<<(HD * HD) / 1024, 256, 0, stream>>>(wv_bf, wv, HD * HD);
  conv_f2b<<<(ID * HD) / 1024, 256, 0, stream>>>(W0_bf, w0i, ID * HD);
  conv_f2b<<<(HD * ID) / 1024, 256, 0, stream>>>(W1_bf, w1i, HD * ID);
  trans_f2b<<<dim3(ID / 64, HD / 64), 256, 0, stream>>>(W1t_bf, w1i, HD, ID);
  dots_kernel<<<256, 256, 0, stream>>>(x, aw, tw, ew, dotA, dotT, dotE);
  coeff_kernel<<<1, 256, 0, stream>>>(dotA, dotT, dotE, betaA, etaA, thetaA);

  // ---- sequential scan ----
  for (int c = 0; c < NCHUNK; ++c) {
    conv_chunk<<<ROWS, 256, 0, stream>>>(xc_bf, x, c);
    // k = rmsnorm(silu(xc@wk^T))*kn
    mfma_nt_64<<<dim3(HD / 64, ROWS / 64), 256, 0, stream>>>(zkv, xc_bf, wk_bf, ROWS, HD, HD);
    post_norm_silu<<<ROWS, 256, 0, stream>>>(kcb, kcb_bf, zkv, kn);
    // zv raw (silu applied inside loss_grad)
    mfma_nt_64<<<dim3(HD / 64, ROWS / 64), 256, 0, stream>>>(zkv, xc_bf, wv_bf, ROWS, HD, HD);
    trans_f2b<<<dim3(HD / 64, ROWS / 64), 256, 0, stream>>>(kcbt_bf, kcb, ROWS, HD);
    // fwd MLP
    mfma_nt_64<<<dim3(ID / 64, ROWS / 64), 256, 0, stream>>>(zfw, kcb_bf, W0_bf, ROWS, ID, HD);
    silu_bf<<<(ROWS * ID) / 1024, 256, 0, stream>>>(hfw_bf, zfw, ROWS * ID);
    trans_b2b<<<dim3(ID / 64, ROWS / 64), 256, 0, stream>>>(hfwt_bf, hfw_bf, ROWS, ID);
    mfma_nt_64<<<dim3(HD / 64, ROWS / 64), 256, 0, stream>>>(ybuf, hfw_bf, W1_bf, ROWS, HD, ID);
    // bwd
    loss_grad<<<ROWS, 256, 0, stream>>>(ybuf, kcb, zkv, memLn, thetaA, c, gbuf, dYb, dY_bf, srow);
    hipMemsetAsync(Gln, 0, HD * 4, stream);
    gln_kernel<<<dim3(HD / 256, 8), 256, 0, stream>>>(gbuf, ybuf, srow, Gln);
    trans_f2b<<<dim3(HD / 64, ROWS / 64), 256, 0, stream>>>(dYt_bf, dYb, ROWS, HD);
    mfma_nt_128<<<dim3(ID / 128, HD / 128), 256, 0, stream>>>(Gw1, dYt_bf, hfwt_bf, HD, ID, ROWS);
    mfma_nt_64<<<dim3(ID / 64, ROWS / 64), 256, 0, stream>>>(dHb, dY_bf, W1t_bf, ROWS, ID, HD);
    trans_silu_bwd<<<dim3(ID / 64, ROWS / 64), 256, 0, stream>>>(dHt_bf, dHb, zfw, ROWS, ID);
    mfma_nt_128<<<dim3(HD / 128, ID / 128), 256, 0, stream>>>(Gw0, dHt_bf, kcbt_bf, ID, HD, ROWS);
    // clip + update
    hipMemsetAsync(nsq, 0, 4, stream);
    norm_reduce<<<1024, 256, 0, stream>>>(Gw0, Gw1, Gln, nsq);
    update_kernel<<<(2 * ID * HD + HD) / 256, 256, 0, stream>>>(
        memW0, memW1, memLn, surpW0, surpW1, surpLn, Gw0, Gw1, Gln, W0_bf, W1_bf,
        etaA, betaA, c, nsq);
    trans_f2b<<<dim3(ID / 64, HD / 64), 256, 0, stream>>>(W1t_bf, memW1, HD, ID);
  }

  // ---- retrieval (8 blocks of 2048 rows); reuse dead scan buffers ----
  const int RB = 2048;
  u16*   xq_bf = (u16*)dHb;           // 4 MB
  float* zq    = surpW0;              // 8 MB
  float* qb    = surpW1;              // 8 MB
  u16*   qb_bf = (u16*)gbuf;          // gbuf+dYb = 4 MB
  float* z2    = Gw0;                 // Gw0+Gw1 = 16 MB
  u16*   h_bf  = (u16*)memW0;         // 8 MB
  float* y2    = memW1;               // 8 MB
  for (int blk = 0; blk < (NB * SEQ) / RB; ++blk) {
    const float* xb = x + (size_t)blk * RB * HD;
    conv_f2b<<<(RB * HD) / 1024, 256, 0, stream>>>(xq_bf, xb, RB * HD);
    mfma_nt_128<<<dim3(HD / 128, RB / 128), 256, 0, stream>>>(zq, xq_bf, wq_bf, RB, HD, HD);
    post_norm_silu<<<RB, 256, 0, stream>>>(qb, qb_bf, zq, qn);
    mfma_nt_128<<<dim3(ID / 128, RB / 128), 256, 0, stream>>>(z2, qb_bf, W0_bf, RB, ID, HD);
    silu_bf<<<(RB * ID) / 1024, 256, 0, stream>>>(h_bf, z2, RB * ID);
    mfma_nt_128<<<dim3(HD / 128, RB / 128), 256, 0, stream>>>(y2, h_bf, W1_bf, RB, HD, ID);
    final_out_kernel<<<RB, 256, 0, stream>>>(out + (size_t)blk * RB * HD, qb, y2, memLn);
  }
}

// Round 3
// 6309.800 us; speedup vs baseline: 2.9016x; 1.1625x over previous
//
#include <hip/hip_runtime.h>

#define HD 1024
#define ID 2048
#define NCHUNK 32
#define CHUNKSZ 64
#define NB 8
#define SEQ 2048
#define ROWS 512
#define MTOT 524288.0f
#define EPSF 1e-6f

typedef unsigned short u16;
typedef unsigned int u32;
typedef short bf16x8 __attribute__((ext_vector_type(8)));
typedef float f32x4 __attribute__((ext_vector_type(4)));

__device__ __forceinline__ float sigmoidf_(float x) { return 1.f / (1.f + expf(-x)); }
__device__ __forceinline__ float siluf_(float x)    { return x / (1.f + expf(-x)); }
__device__ __forceinline__ float silu_d_(float z)   { float sg = sigmoidf_(z); return sg * (1.f + z * (1.f - sg)); }

__device__ __forceinline__ u16 f2b(float f) {
  union { float f; u32 u; } v; v.f = f;
  return (u16)((v.u + 0x7fffu + ((v.u >> 16) & 1u)) >> 16);
}
__device__ __forceinline__ u32 pack2(float a, float b) { return (u32)f2b(a) | ((u32)f2b(b) << 16); }

__device__ __forceinline__ float block_reduce_sum(float v, float* s4) {
  #pragma unroll
  for (int off = 32; off > 0; off >>= 1) v += __shfl_down(v, off);
  int lane = threadIdx.x & 63, wid = threadIdx.x >> 6;
  if (lane == 0) s4[wid] = v;
  __syncthreads();
  float r = s4[0] + s4[1] + s4[2] + s4[3];
  __syncthreads();
  return r;
}

// ---------------------------------------------------------------------------
// 64x64-tile NT MFMA GEMM, templated epilogue + A-source.
// EPI: 0=C fp32; 1=C fp32 + Cb=f2b(silu(acc)); 2=Cb=f2b(acc*silu_d(Z)) only;
//      3=C fp32 + atomicAdd(block sum acc^2 -> nsqc)
// AF32: A is fp32 (converted in staging), with optional chunk row-remap.
// blockIdx.z selects (B0,C) vs (B1,C1) — used to fuse wk/wv projections.
// ---------------------------------------------------------------------------
template<int EPI, bool AF32>
__global__ __launch_bounds__(256) void gemm64_t(
    float* __restrict__ C, u16* __restrict__ Cb,
    const u16* __restrict__ A, const float* __restrict__ Af,
    const u16* __restrict__ B0, const u16* __restrict__ B1,
    const float* __restrict__ Z, float* __restrict__ C1,
    int M, int N, int K, int chunk, float* __restrict__ nsqc)
{
  __shared__ __align__(16) u16 As[64 * 40];
  __shared__ __align__(16) u16 Bs[64 * 40];
  __shared__ float s4[4];
  const int tid = threadIdx.x;
  const int lane = tid & 63, wave = tid >> 6;
  const int wr = wave >> 1, wc = wave & 1;
  const int l15 = lane & 15, q = lane >> 4;
  const int m0 = blockIdx.y * 64, n0 = blockIdx.x * 64;
  const u16* Bsel = blockIdx.z ? B1 : B0;
  float* Csel = blockIdx.z ? C1 : C;

  const int srow = tid >> 2, c8 = (tid & 3) * 8;
  int arow = m0 + srow;
  if (chunk >= 0) arow = (arow >> 6) * SEQ + chunk * CHUNKSZ + (arow & 63);
  const u16*   Abp = AF32 ? nullptr : (A + (size_t)arow * K + c8);
  const float* Afp = AF32 ? (Af + (size_t)arow * K + c8) : nullptr;
  const u16*   Bp  = Bsel + (size_t)(n0 + srow) * K + c8;
  u16* Asw = &As[srow * 40 + c8];
  u16* Bsw = &Bs[srow * 40 + c8];

  f32x4 acc[2][2] = {};
  for (int k0 = 0; k0 < K; k0 += 32) {
    if (AF32) {
      float4 f0 = *(const float4*)(Afp + k0);
      float4 f1 = *(const float4*)(Afp + k0 + 4);
      uint4 o; o.x = pack2(f0.x, f0.y); o.y = pack2(f0.z, f0.w);
      o.z = pack2(f1.x, f1.y); o.w = pack2(f1.z, f1.w);
      *(uint4*)Asw = o;
    } else {
      *(uint4*)Asw = *(const uint4*)(Abp + k0);
    }
    *(uint4*)Bsw = *(const uint4*)(Bp + k0);
    __syncthreads();
    bf16x8 af[2], bg[2];
    #pragma unroll
    for (int i = 0; i < 2; ++i) af[i] = *(const bf16x8*)&As[(wr * 32 + i * 16 + l15) * 40 + q * 8];
    #pragma unroll
    for (int j = 0; j < 2; ++j) bg[j] = *(const bf16x8*)&Bs[(wc * 32 + j * 16 + l15) * 40 + q * 8];
    #pragma unroll
    for (int i = 0; i < 2; ++i)
      #pragma unroll
      for (int j = 0; j < 2; ++j)
        acc[i][j] = __builtin_amdgcn_mfma_f32_16x16x32_bf16(af[i], bg[j], acc[i][j], 0, 0, 0);
    __syncthreads();
  }

  float ssq = 0.f;
  #pragma unroll
  for (int i = 0; i < 2; ++i) {
    int r = m0 + wr * 32 + i * 16 + q * 4;
    #pragma unroll
    for (int j = 0; j < 2; ++j) {
      int col = n0 + wc * 32 + j * 16 + l15;
      #pragma unroll
      for (int t = 0; t < 4; ++t) {
        float v = acc[i][j][t];
        size_t o = (size_t)(r + t) * N + col;
        if (EPI == 0) Csel[o] = v;
        if (EPI == 1) { C[o] = v; Cb[o] = f2b(siluf_(v)); }
        if (EPI == 2) { Cb[o] = f2b(v * silu_d_(Z[o])); }
        if (EPI == 3) { C[o] = v; ssq += v * v; }
      }
    }
  }
  if (EPI == 3) {
    float tot = block_reduce_sum(ssq, s4);
    if (tid == 0) atomicAdd(nsqc, tot);
  }
}

// 32x64-tile NT GEMM (128 threads) — for M=512,N=1024 shapes needing 256 blocks
__global__ __launch_bounds__(128) void gemm_y32(
    float* __restrict__ C, const u16* __restrict__ A, const u16* __restrict__ B,
    int M, int N, int K)
{
  __shared__ __align__(16) u16 As[32 * 40];
  __shared__ __align__(16) u16 Bs[64 * 40];
  const int tid = threadIdx.x;
  const int lane = tid & 63, wc = tid >> 6;
  const int l15 = lane & 15, q = lane >> 4;
  const int m0 = blockIdx.y * 32, n0 = blockIdx.x * 64;

  const int srow = tid >> 2, c8 = (tid & 3) * 8;   // srow 0..31
  const u16* Ap  = A + (size_t)(m0 + srow) * K + c8;
  const u16* Bp0 = B + (size_t)(n0 + srow) * K + c8;
  const u16* Bp1 = B + (size_t)(n0 + srow + 32) * K + c8;
  u16* Asw  = &As[srow * 40 + c8];
  u16* Bsw0 = &Bs[srow * 40 + c8];
  u16* Bsw1 = &Bs[(srow + 32) * 40 + c8];

  f32x4 acc[2][2] = {};
  for (int k0 = 0; k0 < K; k0 += 32) {
    *(uint4*)Asw  = *(const uint4*)(Ap + k0);
    *(uint4*)Bsw0 = *(const uint4*)(Bp0 + k0);
    *(uint4*)Bsw1 = *(const uint4*)(Bp1 + k0);
    __syncthreads();
    bf16x8 af[2], bg[2];
    #pragma unroll
    for (int i = 0; i < 2; ++i) af[i] = *(const bf16x8*)&As[(i * 16 + l15) * 40 + q * 8];
    #pragma unroll
    for (int j = 0; j < 2; ++j) bg[j] = *(const bf16x8*)&Bs[(wc * 32 + j * 16 + l15) * 40 + q * 8];
    #pragma unroll
    for (int i = 0; i < 2; ++i)
      #pragma unroll
      for (int j = 0; j < 2; ++j)
        acc[i][j] = __builtin_amdgcn_mfma_f32_16x16x32_bf16(af[i], bg[j], acc[i][j], 0, 0, 0);
    __syncthreads();
  }
  #pragma unroll
  for (int i = 0; i < 2; ++i) {
    int r = m0 + i * 16 + q * 4;
    #pragma unroll
    for (int j = 0; j < 2; ++j) {
      int col = n0 + wc * 32 + j * 16 + l15;
      #pragma unroll
      for (int t = 0; t < 4; ++t)
        C[(size_t)(r + t) * N + col] = acc[i][j][t];
    }
  }
}

// 128x128-tile NT GEMM. EPI: 0 = C fp32; 1 = Cb = f2b(silu(acc)) only.
template<int EPI, bool AF32>
__global__ __launch_bounds__(256) void gemm128_t(
    float* __restrict__ C, u16* __restrict__ Cb,
    const u16* __restrict__ A, const float* __restrict__ Af,
    const u16* __restrict__ B, int M, int N, int K)
{
  __shared__ __align__(16) u16 As[128 * 40];
  __shared__ __align__(16) u16 Bs[128 * 40];
  const int tid = threadIdx.x;
  const int lane = tid & 63, wave = tid >> 6;
  const int wr = wave >> 1, wc = wave & 1;
  const int l15 = lane & 15, q = lane >> 4;
  const int m0 = blockIdx.y * 128, n0 = blockIdx.x * 128;

  f32x4 acc[4][4] = {};
  for (int k0 = 0; k0 < K; k0 += 32) {
    #pragma unroll
    for (int it = 0; it < 2; ++it) {
      int cid = tid + it * 256;
      int row = cid >> 2, c8 = (cid & 3) * 8;
      if (AF32) {
        const float* ap = Af + (size_t)(m0 + row) * K + k0 + c8;
        float4 f0 = *(const float4*)ap;
        float4 f1 = *(const float4*)(ap + 4);
        uint4 o; o.x = pack2(f0.x, f0.y); o.y = pack2(f0.z, f0.w);
        o.z = pack2(f1.x, f1.y); o.w = pack2(f1.z, f1.w);
        *(uint4*)&As[row * 40 + c8] = o;
      } else {
        *(uint4*)&As[row * 40 + c8] = *(const uint4*)&A[(size_t)(m0 + row) * K + k0 + c8];
      }
      *(uint4*)&Bs[row * 40 + c8] = *(const uint4*)&B[(size_t)(n0 + row) * K + k0 + c8];
    }
    __syncthreads();
    bf16x8 af[4], bg[4];
    #pragma unroll
    for (int i = 0; i < 4; ++i) af[i] = *(const bf16x8*)&As[(wr * 64 + i * 16 + l15) * 40 + q * 8];
    #pragma unroll
    for (int j = 0; j < 4; ++j) bg[j] = *(const bf16x8*)&Bs[(wc * 64 + j * 16 + l15) * 40 + q * 8];
    #pragma unroll
    for (int i = 0; i < 4; ++i)
      #pragma unroll
      for (int j = 0; j < 4; ++j)
        acc[i][j] = __builtin_amdgcn_mfma_f32_16x16x32_bf16(af[i], bg[j], acc[i][j], 0, 0, 0);
    __syncthreads();
  }
  #pragma unroll
  for (int i = 0; i < 4; ++i) {
    int r = m0 + wr * 64 + i * 16 + q * 4;
    #pragma unroll
    for (int j = 0; j < 4; ++j) {
      int col = n0 + wc * 64 + j * 16 + l15;
      #pragma unroll
      for (int t = 0; t < 4; ++t) {
        size_t o = (size_t)(r + t) * N + col;
        if (EPI == 0) C[o] = acc[i][j][t];
        if (EPI == 1) Cb[o] = f2b(siluf_(acc[i][j][t]));
      }
    }
  }
}

// ---------------------------------------------------------------------------
// setup conversions
// ---------------------------------------------------------------------------
__global__ __launch_bounds__(256) void conv_f2b(u16* __restrict__ dst, const float* __restrict__ src, int n) {
  int i = (blockIdx.x * 256 + threadIdx.x) * 4;
  if (i < n) {
    float4 v = *(const float4*)&src[i];
    uint2 o; o.x = pack2(v.x, v.y); o.y = pack2(v.z, v.w);
    *(uint2*)&dst[i] = o;
  }
}

__global__ __launch_bounds__(256) void trans_f2b(u16* __restrict__ dst, const float* __restrict__ src, int R, int C) {
  __shared__ u16 t[64][66];
  int r0 = blockIdx.y * 64, c0 = blockIdx.x * 64;
  #pragma unroll
  for (int it = 0; it < 16; ++it) {
    int idx = threadIdx.x + it * 256;
    int r = idx >> 6, c = idx & 63;
    t[c][r] = f2b(src[(size_t)(r0 + r) * C + c0 + c]);
  }
  __syncthreads();
  #pragma unroll
  for (int it = 0; it < 16; ++it) {
    int idx = threadIdx.x + it * 256;
    int r = idx >> 6, c = idx & 63;
    dst[(size_t)(c0 + r) * R + r0 + c] = t[r][c];
  }
}

// batched 64x64 bf16 transpose of the 4 scan tensors (768 tiles total)
__global__ __launch_bounds__(256) void trans4(
    const u16* __restrict__ kcb_bf, u16* __restrict__ kcbt,
    const u16* __restrict__ hfw_bf, u16* __restrict__ hfwt,
    const u16* __restrict__ dY_bf,  u16* __restrict__ dYt,
    const u16* __restrict__ dH_bf,  u16* __restrict__ dHt)
{
  int t = blockIdx.x;
  const u16* src; u16* dst; int C; int ti;
  if (t < 128)      { src = kcb_bf; dst = kcbt; C = 1024; ti = t; }
  else if (t < 384) { src = hfw_bf; dst = hfwt; C = 2048; ti = t - 128; }
  else if (t < 512) { src = dY_bf;  dst = dYt;  C = 1024; ti = t - 384; }
  else              { src = dH_bf;  dst = dHt;  C = 2048; ti = t - 512; }
  const int R = 512;
  int tpr = C >> 6;
  int r0 = (ti / tpr) * 64, c0 = (ti % tpr) * 64;
  __shared__ u16 tl[64][72];
  #pragma unroll
  for (int it = 0; it < 2; ++it) {
    int u = threadIdx.x + it * 256;          // 512 units of 8 elems
    int r = u >> 3, cg = (u & 7) * 8;
    uint4 v = *(const uint4*)&src[(size_t)(r0 + r) * C + c0 + cg];
    const u16* e = (const u16*)&v;
    #pragma unroll
    for (int k = 0; k < 8; ++k) tl[cg + k][r] = e[k];
  }
  __syncthreads();
  #pragma unroll
  for (int it = 0; it < 2; ++it) {
    int u = threadIdx.x + it * 256;
    int rr = u >> 3, gg = (u & 7) * 8;
    *(uint4*)&dst[(size_t)(c0 + rr) * R + r0 + gg] = *(uint4*)&tl[rr][gg];
  }
}

// ---------------------------------------------------------------------------
// small fused kernels
// ---------------------------------------------------------------------------
__global__ __launch_bounds__(256) void dots_kernel(
    const float* __restrict__ x, const float* __restrict__ aw,
    const float* __restrict__ tw, const float* __restrict__ ew,
    float* __restrict__ dA, float* __restrict__ dT, float* __restrict__ dE)
{
  int b = blockIdx.x >> 5, c = blockIdx.x & 31;
  const float* base = x + ((size_t)b * SEQ + (size_t)c * CHUNKSZ) * HD;
  float a = 0.f, t = 0.f, e = 0.f;
  for (int it = 0; it < 64; ++it) {
    int j = (it * 256 + threadIdx.x) * 4;
    float4 xv = *(const float4*)&base[j];
    float4 av = *(const float4*)&aw[j];
    float4 tv = *(const float4*)&tw[j];
    float4 ev = *(const float4*)&ew[j];
    a += xv.x * av.x + xv.y * av.y + xv.z * av.z + xv.w * av.w;
    t += xv.x * tv.x + xv.y * tv.y + xv.z * tv.z + xv.w * tv.w;
    e += xv.x * ev.x + xv.y * ev.y + xv.z * ev.z + xv.w * ev.w;
  }
  __shared__ float s4[4];
  a = block_reduce_sum(a, s4);
  t = block_reduce_sum(t, s4);
  e = block_reduce_sum(e, s4);
  if (threadIdx.x == 0) { dA[blockIdx.x] = a; dT[blockIdx.x] = t; dE[blockIdx.x] = e; }
}

__global__ __launch_bounds__(256) void coeff_kernel(
    const float* __restrict__ dA, const float* __restrict__ dT, const float* __restrict__ dE,
    float* __restrict__ betaA, float* __restrict__ etaA, float* __restrict__ thetaA)
{
  int t = threadIdx.x;
  if (t < 256) thetaA[t] = sigmoidf_(dT[t]) * 0.01f;
  if (t < 32) {
    float sa = 0.f, se = 0.f;
    for (int b = 0; b < NB; ++b) { sa += dA[b * 32 + t]; se += dE[b * 32 + t]; }
    betaA[t] = 1.f - sigmoidf_(sa / 8.f);
    etaA[t]  = sigmoidf_(se / 8.f);
  }
}

__global__ __launch_bounds__(256) void post_norm_silu(
    float* __restrict__ dst, u16* __restrict__ dstb,
    const float* __restrict__ src, const float* __restrict__ nw)
{
  size_t off = (size_t)blockIdx.x * HD;
  float sv[4]; float ss = 0.f;
  #pragma unroll
  for (int i = 0; i < 4; ++i) {
    float z = src[off + i * 256 + threadIdx.x];
    float s = siluf_(z);
    sv[i] = s; ss += s * s;
  }
  __shared__ float s4[4];
  ss = block_reduce_sum(ss, s4);
  float rs = rsqrtf(ss / (float)HD + EPSF);
  #pragma unroll
  for (int i = 0; i < 4; ++i) {
    int j = i * 256 + threadIdx.x;
    float o = sv[i] * rs * nw[j];
    dst[off + j] = o;
    dstb[off + j] = f2b(o);
  }
}

__global__ __launch_bounds__(256) void loss_grad(
    const float* __restrict__ y, const float* __restrict__ kc, const float* __restrict__ zvraw,
    const float* __restrict__ ln, const float* __restrict__ thetaA, int c,
    float* __restrict__ g, u16* __restrict__ dYbf, float* __restrict__ srow)
{
  int r = blockIdx.x;
  size_t off = (size_t)r * HD;
  float th = thetaA[(r >> 6) * 32 + c];
  float yv[4], lnv[4];
  float ss = 0.f;
  #pragma unroll
  for (int i = 0; i < 4; ++i) {
    int j = i * 256 + threadIdx.x;
    yv[i] = y[off + j];
    lnv[i] = ln[j];
    ss += yv[i] * yv[i];
  }
  __shared__ float s4[4];
  ss = block_reduce_sum(ss, s4);
  float s = rsqrtf(ss / (float)HD + EPSF);
  float coef = 2.f * th / MTOT;
  float gv[4]; float t = 0.f;
  #pragma unroll
  for (int i = 0; i < 4; ++i) {
    int j = i * 256 + threadIdx.x;
    float pred = kc[off + j] + yv[i] * s * lnv[i];
    float vv = siluf_(zvraw[off + j]);
    float gg = coef * (pred - vv);
    gv[i] = gg;
    g[off + j] = gg;
    t += gg * lnv[i] * yv[i];
  }
  t = block_reduce_sum(t, s4);
  float c3 = s * s * s * t * (1.f / (float)HD);
  #pragma unroll
  for (int i = 0; i < 4; ++i) {
    int j = i * 256 + threadIdx.x;
    dYbf[off + j] = f2b(s * gv[i] * lnv[i] - c3 * yv[i]);
  }
  if (threadIdx.x == 0) srow[r] = s;
}

// Gln (no atomics into Gln) + fold sum(Gln^2) into nsq[c].  grid 8, 256 thr.
__global__ __launch_bounds__(256) void gln_kernel(
    const float* __restrict__ g, const float* __restrict__ y,
    const float* __restrict__ srow, float* __restrict__ Gln, float* __restrict__ nsqc)
{
  int j = blockIdx.x * 128 + (threadIdx.x & 127);
  int half = threadIdx.x >> 7;
  float acc = 0.f;
  for (int rr = 0; rr < 256; ++rr) {
    int r = half * 256 + rr;
    size_t o = (size_t)r * HD + j;
    acc += g[o] * y[o] * srow[r];
  }
  __shared__ float part[128];
  if (!half) part[threadIdx.x] = acc;
  __syncthreads();
  if (half) {
    float tot = acc + part[threadIdx.x - 128];
    Gln[j] = tot;
    float sq = tot * tot;
    #pragma unroll
    for (int off = 32; off > 0; off >>= 1) sq += __shfl_down(sq, off);
    if ((threadIdx.x & 63) == 0) atomicAdd(nsqc, sq);
  }
}

// W0 (vec4) + ln update; writes W0_bf fused
__global__ __launch_bounds__(256) void update_flat(
    float* __restrict__ mw0, float* __restrict__ sw0, const float* __restrict__ g0,
    u16* __restrict__ w0b,
    float* __restrict__ mln, float* __restrict__ sln, const float* __restrict__ gl,
    const float* __restrict__ etaA, const float* __restrict__ betaA, int c,
    const float* __restrict__ nsqc)
{
  int idx4 = (blockIdx.x * 256 + threadIdx.x) * 4;
  float clip = fminf(1.0f / (sqrtf(*nsqc) + 1e-6f), 1.0f);
  float eta = etaA[c], beta = betaA[c];
  if (idx4 < ID * HD) {
    float4 s = *(float4*)&sw0[idx4];
    float4 g = *(const float4*)&g0[idx4];
    float4 m = *(float4*)&mw0[idx4];
    s.x = eta * s.x - clip * g.x; m.x = beta * m.x + s.x;
    s.y = eta * s.y - clip * g.y; m.y = beta * m.y + s.y;
    s.z = eta * s.z - clip * g.z; m.z = beta * m.z + s.z;
    s.w = eta * s.w - clip * g.w; m.w = beta * m.w + s.w;
    *(float4*)&sw0[idx4] = s;
    *(float4*)&mw0[idx4] = m;
    uint2 o; o.x = pack2(m.x, m.y); o.y = pack2(m.z, m.w);
    *(uint2*)&w0b[idx4] = o;
  } else {
    int i = idx4 - ID * HD;
    if (i < HD) {
      #pragma unroll
      for (int k = 0; k < 4; ++k) {
        float ns = eta * sln[i + k] - clip * gl[i + k];
        sln[i + k] = ns;
        mln[i + k] = beta * mln[i + k] + ns;
      }
    }
  }
}

// tiled W1 update: writes mw1/sw1 fp32, W1_bf, and W1t_bf (transposed) fused
__global__ __launch_bounds__(256) void update_w1(
    float* __restrict__ mw1, float* __restrict__ sw1, const float* __restrict__ g1,
    u16* __restrict__ w1b, u16* __restrict__ w1tb,
    const float* __restrict__ etaA, const float* __restrict__ betaA, int c,
    const float* __restrict__ nsqc)
{
  int r0 = blockIdx.y * 64, c0 = blockIdx.x * 64;
  float clip = fminf(1.0f / (sqrtf(*nsqc) + 1e-6f), 1.0f);
  float eta = etaA[c], beta = betaA[c];
  __shared__ u16 tl[64][72];
  #pragma unroll
  for (int it = 0; it < 4; ++it) {
    int u = threadIdx.x + it * 256;          // 1024 units of 4 elems
    int r = u >> 4, cg = (u & 15) * 4;
    size_t i = (size_t)(r0 + r) * ID + c0 + cg;
    float4 s = *(float4*)&sw1[i];
    float4 g = *(const float4*)&g1[i];
    float4 m = *(float4*)&mw1[i];
    s.x = eta * s.x - clip * g.x; m.x = beta * m.x + s.x;
    s.y = eta * s.y - clip * g.y; m.y = beta * m.y + s.y;
    s.z = eta * s.z - clip * g.z; m.z = beta * m.z + s.z;
    s.w = eta * s.w - clip * g.w; m.w = beta * m.w + s.w;
    *(float4*)&sw1[i] = s;
    *(float4*)&mw1[i] = m;
    u16 b0 = f2b(m.x), b1 = f2b(m.y), b2 = f2b(m.z), b3 = f2b(m.w);
    uint2 o; o.x = (u32)b0 | ((u32)b1 << 16); o.y = (u32)b2 | ((u32)b3 << 16);
    *(uint2*)&w1b[i] = o;
    tl[cg + 0][r] = b0; tl[cg + 1][r] = b1; tl[cg + 2][r] = b2; tl[cg + 3][r] = b3;
  }
  __syncthreads();
  #pragma unroll
  for (int it = 0; it < 2; ++it) {
    int u = threadIdx.x + it * 256;          // 512 units of 8 elems
    int rr = u >> 3, gg = (u & 7) * 8;
    *(uint4*)&w1tb[(size_t)(c0 + rr) * HD + r0 + gg] = *(uint4*)&tl[rr][gg];
  }
}

__global__ __launch_bounds__(256) void final_out_kernel(
    float* __restrict__ out, const float* __restrict__ qb,
    const float* __restrict__ y2, const float* __restrict__ ln)
{
  size_t off = (size_t)blockIdx.x * HD;
  float yv[4]; float ss = 0.f;
  #pragma unroll
  for (int i = 0; i < 4; ++i) {
    yv[i] = y2[off + i * 256 + threadIdx.x];
    ss += yv[i] * yv[i];
  }
  __shared__ float s4[4];
  ss = block_reduce_sum(ss, s4);
  float s = rsqrtf(ss / (float)HD + EPSF);
  #pragma unroll
  for (int i = 0; i < 4; ++i) {
    int j = i * 256 + threadIdx.x;
    out[off + j] = qb[off + j] + yv[i] * s * ln[j];
  }
}

// ---------------------------------------------------------------------------
// launch
// ---------------------------------------------------------------------------
extern "C" void kernel_launch(void* const* d_in, const int* in_sizes, int n_in,
                              void* d_out, int out_size, void* d_ws, size_t ws_size,
                              hipStream_t stream) {
  const float* x   = (const float*)d_in[0];
  const float* wq  = (const float*)d_in[1];
  const float* wk  = (const float*)d_in[2];
  const float* wv  = (const float*)d_in[3];
  const float* qn  = (const float*)d_in[4];
  const float* kn  = (const float*)d_in[5];
  const float* aw  = (const float*)d_in[6];
  const float* tw  = (const float*)d_in[7];
  const float* ew  = (const float*)d_in[8];
  const float* w0i = (const float*)d_in[9];
  const float* w1i = (const float*)d_in[10];
  const float* lni = (const float*)d_in[11];
  float* out = (float*)d_out;

  float* p = (float*)d_ws;
  auto alloc = [&](size_t n) { n = (n + 63) & ~(size_t)63; float* r = p; p += n; return r; };
  float* memW0  = alloc((size_t)ID * HD);
  float* memW1  = alloc((size_t)HD * ID);
  float* memLn  = alloc(HD);
  float* surpW0 = alloc((size_t)ID * HD);
  float* surpW1 = alloc((size_t)HD * ID);
  float* surpLn = alloc(HD);
  float* Gw0    = alloc((size_t)ID * HD);
  float* Gw1    = alloc((size_t)HD * ID);
  float* Gln    = alloc(HD);
  float* zk     = alloc((size_t)ROWS * HD);
  float* zv     = alloc((size_t)ROWS * HD);
  float* zfw    = alloc((size_t)ROWS * ID);
  float* kcb    = alloc((size_t)ROWS * HD);
  float* ybuf   = alloc((size_t)ROWS * HD);
  float* gbuf   = alloc((size_t)ROWS * HD);
  float* srow   = alloc(ROWS);
  float* dotA   = alloc(256);
  float* dotT   = alloc(256);
  float* dotE   = alloc(256);
  float* betaA  = alloc(64);
  float* etaA   = alloc(64);
  float* thetaA = alloc(256);
  float* nsq    = alloc(64);   // one slot per chunk

  u16* bp = (u16*)p;
  auto balloc = [&](size_t n) { n = (n + 63) & ~(size_t)63; u16* r = bp; bp += n; return r; };
  u16* wq_bf   = balloc((size_t)HD * HD);
  u16* wk_bf   = balloc((size_t)HD * HD);
  u16* wv_bf   = balloc((size_t)HD * HD);
  u16* W0_bf   = balloc((size_t)ID * HD);
  u16* W1_bf   = balloc((size_t)HD * ID);
  u16* W1t_bf  = balloc((size_t)ID * HD);
  u16* kcb_bf  = balloc((size_t)ROWS * HD);
  u16* kcbt    = balloc((size_t)HD * ROWS);
  u16* hfw_bf  = balloc((size_t)ROWS * ID);
  u16* hfwt    = balloc((size_t)ID * ROWS);
  u16* dY_bf   = balloc((size_t)ROWS * HD);
  u16* dYt     = balloc((size_t)HD * ROWS);
  u16* dH_bf   = balloc((size_t)ROWS * ID);
  u16* dHt     = balloc((size_t)ID * ROWS);
  size_t needed = (size_t)((char*)bp - (char*)d_ws);
  if (needed > ws_size) return;

  // ---- setup ----
  hipMemcpyAsync(memW0, w0i, (size_t)ID * HD * 4, hipMemcpyDeviceToDevice, stream);
  hipMemcpyAsync(memW1, w1i, (size_t)HD * ID * 4, hipMemcpyDeviceToDevice, stream);
  hipMemcpyAsync(memLn, lni, (size_t)HD * 4, hipMemcpyDeviceToDevice, stream);
  hipMemsetAsync(surpW0, 0, ((size_t)ID * HD * 2 + HD + 64) * 4, stream);  // surp block
  hipMemsetAsync(nsq, 0, 64 * 4, stream);
  conv_f2b<<<(HD * HD) / 1024, 256, 0, stream>>>(wq_bf, wq, HD * HD);
  conv_f2b<<<(HD * HD) / 1024, 256, 0, stream>>>(wk_bf, wk, HD * HD);
  conv_f2b<<<(HD * HD) / 1024, 256, 0, stream>>>(wv_bf, wv, HD * HD);
  conv_f2b<<<(ID * HD) / 1024, 256, 0, stream>>>(W0_bf, w0i, ID * HD);
  conv_f2b<<<(HD * ID) / 1024, 256, 0, stream>>>(W1_bf, w1i, HD * ID);
  trans_f2b<<<dim3(ID / 64, HD / 64), 256, 0, stream>>>(W1t_bf, w1i, HD, ID);
  dots_kernel<<<256, 256, 0, stream>>>(x, aw, tw, ew, dotA, dotT, dotE);
  coeff_kernel<<<1, 256, 0, stream>>>(dotA, dotT, dotE, betaA, etaA, thetaA);

  // ---- sequential scan ----
  for (int c = 0; c < NCHUNK; ++c) {
    // zk = xc@wk^T, zv = xc@wv^T (one launch, z selects), A staged from fp32 x
    gemm64_t<0, true><<<dim3(HD / 64, ROWS / 64, 2), 256, 0, stream>>>(
        zk, nullptr, nullptr, x, wk_bf, wv_bf, nullptr, zv, ROWS, HD, HD, c, nullptr);
    post_norm_silu<<<ROWS, 256, 0, stream>>>(kcb, kcb_bf, zk, kn);
    // zfw = kcb@W0^T (+ hfw_bf = silu fused)
    gemm64_t<1, false><<<dim3(ID / 64, ROWS / 64, 1), 256, 0, stream>>>(
        zfw, hfw_bf, kcb_bf, nullptr, W0_bf, W0_bf, nullptr, nullptr, ROWS, ID, HD, -1, nullptr);
    // ybuf = hfw@W1^T  (32x64 tile -> 256 blocks)
    gemm_y32<<<dim3(HD / 64, ROWS / 32), 128, 0, stream>>>(ybuf, hfw_bf, W1_bf, ROWS, HD, ID);
    loss_grad<<<ROWS, 256, 0, stream>>>(ybuf, kcb, zv, memLn, thetaA, c, gbuf, dY_bf, srow);
    gln_kernel<<<8, 256, 0, stream>>>(gbuf, ybuf, srow, Gln, nsq + c);
    // dH_bf = f2b((dY@W1) * silu'(zfw))
    gemm64_t<2, false><<<dim3(ID / 64, ROWS / 64, 1), 256, 0, stream>>>(
        nullptr, dH_bf, dY_bf, nullptr, W1t_bf, W1t_bf, zfw, nullptr, ROWS, ID, HD, -1, nullptr);
    trans4<<<768, 256, 0, stream>>>(kcb_bf, kcbt, hfw_bf, hfwt, dY_bf, dYt, dH_bf, dHt);
    // Gw1 = dYt @ hfwt^T (K=512), Gw0 = dHt @ kcbt^T — epilogue adds ||g||^2 into nsq[c]
    gemm64_t<3, false><<<dim3(ID / 64, HD / 64, 1), 256, 0, stream>>>(
        Gw1, nullptr, dYt, nullptr, hfwt, hfwt, nullptr, nullptr, HD, ID, ROWS, -1, nsq + c);
    gemm64_t<3, false><<<dim3(HD / 64, ID / 64, 1), 256, 0, stream>>>(
        Gw0, nullptr, dHt, nullptr, kcbt, kcbt, nullptr, nullptr, ID, HD, ROWS, -1, nsq + c);
    update_flat<<<(ID * HD + HD) / 1024, 256, 0, stream>>>(
        memW0, surpW0, Gw0, W0_bf, memLn, surpLn, Gln, etaA, betaA, c, nsq + c);
    update_w1<<<dim3(ID / 64, HD / 64), 256, 0, stream>>>(
        memW1, surpW1, Gw1, W1_bf, W1t_bf, etaA, betaA, c, nsq + c);
  }

  // ---- retrieval (8 x 2048 rows), buffers alias dead scan state ----
  const int RB = 2048;
  float* zq    = surpW0;         // 2M f32
  float* y2    = surpW1;         // 2M f32
  float* qb    = Gw0;            // 2M f32
  u16*   qb_bf = (u16*)Gw1;      // 2M u16
  u16*   h_bf  = (u16*)memW0;    // 4M u16 (= memW0's 8 MB exactly)
  for (int blk = 0; blk < (NB * SEQ) / RB; ++blk) {
    const float* xb = x + (size_t)blk * RB * HD;
    gemm128_t<0, true><<<dim3(HD / 128, RB / 128), 256, 0, stream>>>(
        zq, nullptr, nullptr, xb, wq_bf, RB, HD, HD);
    post_norm_silu<<<RB, 256, 0, stream>>>(qb, qb_bf, zq, qn);
    gemm128_t<1, false><<<dim3(ID / 128, RB / 128), 256, 0, stream>>>(
        nullptr, h_bf, qb_bf, nullptr, W0_bf, RB, ID, HD);
    gemm128_t<0, false><<<dim3(HD / 128, RB / 128), 256, 0, stream>>>(
        y2, nullptr, h_bf, nullptr, W1_bf, RB, HD, ID);
    final_out_kernel<<<RB, 256, 0, stream>>>(out + (size_t)blk * RB * HD, qb, y2, memLn);
  }
}

// Round 4
// 5043.781 us; speedup vs baseline: 3.6299x; 1.2510x over previous
//
#include <hip/hip_runtime.h>

#define HD 1024
#define ID 2048
#define NCHUNK 32
#define CHUNKSZ 64
#define NB 8
#define SEQ 2048
#define ROWS 512
#define MTOT 524288.0f
#define EPSF 1e-6f

typedef unsigned short u16;
typedef unsigned int u32;
typedef short bf16x8 __attribute__((ext_vector_type(8)));
typedef float f32x4 __attribute__((ext_vector_type(4)));

#define GATHER(r, c) ((((r) >> 6) * SEQ) + ((c) * CHUNKSZ) + ((r) & 63))

__device__ __forceinline__ float sigmoidf_(float x) { return 1.f / (1.f + expf(-x)); }
__device__ __forceinline__ float siluf_(float x)    { return x / (1.f + expf(-x)); }
__device__ __forceinline__ float silu_d_(float z)   { float sg = sigmoidf_(z); return sg * (1.f + z * (1.f - sg)); }

__device__ __forceinline__ u16 f2b(float f) {
  union { float f; u32 u; } v; v.f = f;
  return (u16)((v.u + 0x7fffu + ((v.u >> 16) & 1u)) >> 16);
}
__device__ __forceinline__ float b2f(u16 b) {
  union { u32 u; float f; } v; v.u = ((u32)b) << 16; return v.f;
}
__device__ __forceinline__ u32 pack2(float a, float b) { return (u32)f2b(a) | ((u32)f2b(b) << 16); }

__device__ __forceinline__ float block_reduce_sum(float v, float* s4) {
  #pragma unroll
  for (int off = 32; off > 0; off >>= 1) v += __shfl_down(v, off);
  int lane = threadIdx.x & 63, wid = threadIdx.x >> 6;
  if (lane == 0) s4[wid] = v;
  __syncthreads();
  float r = s4[0] + s4[1] + s4[2] + s4[3];
  __syncthreads();
  return r;
}

// ---------------------------------------------------------------------------
// 64x64-tile BK=64 NT GEMM core (bf16 A/B, fp32 acc). LDS stride 72 elems.
// chunk >= 0: A rows gathered per GATHER.
// ---------------------------------------------------------------------------
__device__ __forceinline__ void gemm64_core(
    f32x4 (&acc)[2][2], const u16* __restrict__ A, const u16* __restrict__ B,
    int K, int m0, int n0, int chunk, u16* As, u16* Bs)
{
  const int tid = threadIdx.x;
  const int lane = tid & 63, wave = tid >> 6;
  const int wr = wave >> 1, wc = wave & 1;
  const int l15 = lane & 15, q = lane >> 4;
  const int srow = tid >> 2, c16 = (tid & 3) * 16;
  int arow = m0 + srow;
  if (chunk >= 0) arow = GATHER(arow, chunk);
  const u16* Ap = A + (size_t)arow * K + c16;
  const u16* Bp = B + (size_t)(n0 + srow) * K + c16;
  u16* Aw = As + srow * 72 + c16;
  u16* Bw = Bs + srow * 72 + c16;
  for (int k0 = 0; k0 < K; k0 += 64) {
    *(uint4*)Aw       = *(const uint4*)(Ap + k0);
    *(uint4*)(Aw + 8) = *(const uint4*)(Ap + k0 + 8);
    *(uint4*)Bw       = *(const uint4*)(Bp + k0);
    *(uint4*)(Bw + 8) = *(const uint4*)(Bp + k0 + 8);
    __syncthreads();
    #pragma unroll
    for (int ks = 0; ks < 2; ++ks) {
      bf16x8 af[2], bg[2];
      #pragma unroll
      for (int i = 0; i < 2; ++i) af[i] = *(const bf16x8*)&As[(wr * 32 + i * 16 + l15) * 72 + ks * 32 + q * 8];
      #pragma unroll
      for (int j = 0; j < 2; ++j) bg[j] = *(const bf16x8*)&Bs[(wc * 32 + j * 16 + l15) * 72 + ks * 32 + q * 8];
      #pragma unroll
      for (int i = 0; i < 2; ++i)
        #pragma unroll
        for (int j = 0; j < 2; ++j)
          acc[i][j] = __builtin_amdgcn_mfma_f32_16x16x32_bf16(af[i], bg[j], acc[i][j], 0, 0, 0);
    }
    __syncthreads();
  }
}

// fwd MLP layer-0: C = zfw fp32, Cb = f2b(silu(acc))
__global__ __launch_bounds__(256) void gemm64_fwd(
    float* __restrict__ C, u16* __restrict__ Cb,
    const u16* __restrict__ A, const u16* __restrict__ B, int N, int K, int chunk)
{
  __shared__ __align__(16) u16 As[64 * 72];
  __shared__ __align__(16) u16 Bs[64 * 72];
  const int m0 = blockIdx.y * 64, n0 = blockIdx.x * 64;
  f32x4 acc[2][2] = {};
  gemm64_core(acc, A, B, K, m0, n0, chunk, As, Bs);
  const int lane = threadIdx.x & 63, wave = threadIdx.x >> 6;
  const int wr = wave >> 1, wc = wave & 1;
  const int l15 = lane & 15, q = lane >> 4;
  #pragma unroll
  for (int i = 0; i < 2; ++i) {
    int r = m0 + wr * 32 + i * 16 + q * 4;
    #pragma unroll
    for (int j = 0; j < 2; ++j) {
      int col = n0 + wc * 32 + j * 16 + l15;
      #pragma unroll
      for (int t = 0; t < 4; ++t) {
        float v = acc[i][j][t];
        size_t o = (size_t)(r + t) * N + col;
        C[o] = v;
        Cb[o] = f2b(siluf_(v));
      }
    }
  }
}

// dH: Cb = f2b(acc * silu'(Z))
__global__ __launch_bounds__(256) void gemm64_dh(
    u16* __restrict__ Cb, const u16* __restrict__ A, const u16* __restrict__ B,
    const float* __restrict__ Z, int N, int K)
{
  __shared__ __align__(16) u16 As[64 * 72];
  __shared__ __align__(16) u16 Bs[64 * 72];
  const int m0 = blockIdx.y * 64, n0 = blockIdx.x * 64;
  f32x4 acc[2][2] = {};
  gemm64_core(acc, A, B, K, m0, n0, -1, As, Bs);
  const int lane = threadIdx.x & 63, wave = threadIdx.x >> 6;
  const int wr = wave >> 1, wc = wave & 1;
  const int l15 = lane & 15, q = lane >> 4;
  #pragma unroll
  for (int i = 0; i < 2; ++i) {
    int r = m0 + wr * 32 + i * 16 + q * 4;
    #pragma unroll
    for (int j = 0; j < 2; ++j) {
      int col = n0 + wc * 32 + j * 16 + l15;
      #pragma unroll
      for (int t = 0; t < 4; ++t) {
        size_t o = (size_t)(r + t) * N + col;
        Cb[o] = f2b(acc[i][j][t] * silu_d_(Z[o]));
      }
    }
  }
}

// both weight-grad GEMMs in one launch (flat bid decode); ||g||^2 -> nsqc
__global__ __launch_bounds__(256) void gemm_grads(
    float* __restrict__ Gw1, const u16* __restrict__ dYt, const u16* __restrict__ hfwt,
    float* __restrict__ Gw0, const u16* __restrict__ dHt, const u16* __restrict__ kcbt,
    float* __restrict__ nsqc)
{
  __shared__ __align__(16) u16 As[64 * 72];
  __shared__ __align__(16) u16 Bs[64 * 72];
  __shared__ float s4[4];
  int bid = blockIdx.x;
  float* C; const u16* A; const u16* B; int N, m0, n0;
  if (bid < 512) { A = dYt; B = hfwt; C = Gw1; N = ID; m0 = (bid >> 5) * 64; n0 = (bid & 31) * 64; }
  else { bid -= 512; A = dHt; B = kcbt; C = Gw0; N = HD; m0 = (bid >> 4) * 64; n0 = (bid & 15) * 64; }
  f32x4 acc[2][2] = {};
  gemm64_core(acc, A, B, ROWS, m0, n0, -1, As, Bs);
  const int lane = threadIdx.x & 63, wave = threadIdx.x >> 6;
  const int wr = wave >> 1, wc = wave & 1;
  const int l15 = lane & 15, q = lane >> 4;
  float ssq = 0.f;
  #pragma unroll
  for (int i = 0; i < 2; ++i) {
    int r = m0 + wr * 32 + i * 16 + q * 4;
    #pragma unroll
    for (int j = 0; j < 2; ++j) {
      int col = n0 + wc * 32 + j * 16 + l15;
      #pragma unroll
      for (int t = 0; t < 4; ++t) {
        float v = acc[i][j][t];
        C[(size_t)(r + t) * N + col] = v;
        ssq += v * v;
      }
    }
  }
  float tot = block_reduce_sum(ssq, s4);
  if (threadIdx.x == 0) atomicAdd(nsqc, tot);
}

// 32x64-tile BK=64 NT GEMM (128 threads): y = hfw @ W1^T (K=2048)
__global__ __launch_bounds__(128) void gemm_y32(
    float* __restrict__ C, const u16* __restrict__ A, const u16* __restrict__ B,
    int N, int K)
{
  __shared__ __align__(16) u16 As[32 * 72];
  __shared__ __align__(16) u16 Bs[64 * 72];
  const int tid = threadIdx.x;
  const int lane = tid & 63, wc = tid >> 6;
  const int l15 = lane & 15, q = lane >> 4;
  const int m0 = blockIdx.y * 32, n0 = blockIdx.x * 64;

  const int arow = tid >> 2, ac16 = (tid & 3) * 16;   // 32 rows x 64 cols
  const int brow = tid >> 1, bc32 = (tid & 1) * 32;   // 64 rows x 64 cols
  const u16* Ap = A + (size_t)(m0 + arow) * K + ac16;
  const u16* Bp = B + (size_t)(n0 + brow) * K + bc32;
  u16* Aw = &As[arow * 72 + ac16];
  u16* Bw = &Bs[brow * 72 + bc32];

  f32x4 acc[2][2] = {};
  for (int k0 = 0; k0 < K; k0 += 64) {
    *(uint4*)Aw        = *(const uint4*)(Ap + k0);
    *(uint4*)(Aw + 8)  = *(const uint4*)(Ap + k0 + 8);
    *(uint4*)Bw        = *(const uint4*)(Bp + k0);
    *(uint4*)(Bw + 8)  = *(const uint4*)(Bp + k0 + 8);
    *(uint4*)(Bw + 16) = *(const uint4*)(Bp + k0 + 16);
    *(uint4*)(Bw + 24) = *(const uint4*)(Bp + k0 + 24);
    __syncthreads();
    #pragma unroll
    for (int ks = 0; ks < 2; ++ks) {
      bf16x8 af[2], bg[2];
      #pragma unroll
      for (int i = 0; i < 2; ++i) af[i] = *(const bf16x8*)&As[(i * 16 + l15) * 72 + ks * 32 + q * 8];
      #pragma unroll
      for (int j = 0; j < 2; ++j) bg[j] = *(const bf16x8*)&Bs[(wc * 32 + j * 16 + l15) * 72 + ks * 32 + q * 8];
      #pragma unroll
      for (int i = 0; i < 2; ++i)
        #pragma unroll
        for (int j = 0; j < 2; ++j)
          acc[i][j] = __builtin_amdgcn_mfma_f32_16x16x32_bf16(af[i], bg[j], acc[i][j], 0, 0, 0);
    }
    __syncthreads();
  }
  #pragma unroll
  for (int i = 0; i < 2; ++i) {
    int r = m0 + i * 16 + q * 4;
    #pragma unroll
    for (int j = 0; j < 2; ++j) {
      int col = n0 + wc * 32 + j * 16 + l15;
      #pragma unroll
      for (int t = 0; t < 4; ++t)
        C[(size_t)(r + t) * N + col] = acc[i][j][t];
    }
  }
}

// ---------------------------------------------------------------------------
// 128x128-tile BK=32 NT GEMM (stride-40 LDS).
// EPI 0: C fp32.  1: Cb = f2b(silu(acc)).  2: kv-mode — z=0: Cb=f2b(acc),
// z=1: Cb1=f2b(silu(acc)); B picked by z.
// ---------------------------------------------------------------------------
template<int EPI, bool AF32>
__global__ __launch_bounds__(256) void gemm128_t(
    float* __restrict__ C, u16* __restrict__ Cb, u16* __restrict__ Cb1,
    const u16* __restrict__ A, const float* __restrict__ Af,
    const u16* __restrict__ B0, const u16* __restrict__ B1,
    int M, int N, int K)
{
  __shared__ __align__(16) u16 As[128 * 40];
  __shared__ __align__(16) u16 Bs[128 * 40];
  const int tid = threadIdx.x;
  const int lane = tid & 63, wave = tid >> 6;
  const int wr = wave >> 1, wc = wave & 1;
  const int l15 = lane & 15, q = lane >> 4;
  const int m0 = blockIdx.y * 128, n0 = blockIdx.x * 128;
  const u16* B = (EPI == 2 && blockIdx.z) ? B1 : B0;

  f32x4 acc[4][4] = {};
  for (int k0 = 0; k0 < K; k0 += 32) {
    #pragma unroll
    for (int it = 0; it < 2; ++it) {
      int cid = tid + it * 256;
      int row = cid >> 2, c8 = (cid & 3) * 8;
      if (AF32) {
        const float* ap = Af + (size_t)(m0 + row) * K + k0 + c8;
        float4 f0 = *(const float4*)ap;
        float4 f1 = *(const float4*)(ap + 4);
        uint4 o; o.x = pack2(f0.x, f0.y); o.y = pack2(f0.z, f0.w);
        o.z = pack2(f1.x, f1.y); o.w = pack2(f1.z, f1.w);
        *(uint4*)&As[row * 40 + c8] = o;
      } else {
        *(uint4*)&As[row * 40 + c8] = *(const uint4*)&A[(size_t)(m0 + row) * K + k0 + c8];
      }
      *(uint4*)&Bs[row * 40 + c8] = *(const uint4*)&B[(size_t)(n0 + row) * K + k0 + c8];
    }
    __syncthreads();
    bf16x8 af[4], bg[4];
    #pragma unroll
    for (int i = 0; i < 4; ++i) af[i] = *(const bf16x8*)&As[(wr * 64 + i * 16 + l15) * 40 + q * 8];
    #pragma unroll
    for (int j = 0; j < 4; ++j) bg[j] = *(const bf16x8*)&Bs[(wc * 64 + j * 16 + l15) * 40 + q * 8];
    #pragma unroll
    for (int i = 0; i < 4; ++i)
      #pragma unroll
      for (int j = 0; j < 4; ++j)
        acc[i][j] = __builtin_amdgcn_mfma_f32_16x16x32_bf16(af[i], bg[j], acc[i][j], 0, 0, 0);
    __syncthreads();
  }
  #pragma unroll
  for (int i = 0; i < 4; ++i) {
    int r = m0 + wr * 64 + i * 16 + q * 4;
    #pragma unroll
    for (int j = 0; j < 4; ++j) {
      int col = n0 + wc * 64 + j * 16 + l15;
      #pragma unroll
      for (int t = 0; t < 4; ++t) {
        float v = acc[i][j][t];
        size_t o = (size_t)(r + t) * N + col;
        if (EPI == 0) C[o] = v;
        if (EPI == 1) Cb[o] = f2b(siluf_(v));
        if (EPI == 2) { if (blockIdx.z == 0) Cb[o] = f2b(v); else Cb1[o] = f2b(siluf_(v)); }
      }
    }
  }
}

// ---------------------------------------------------------------------------
// setup conversions
// ---------------------------------------------------------------------------
__global__ __launch_bounds__(256) void conv_f2b(u16* __restrict__ dst, const float* __restrict__ src, int n) {
  int i = (blockIdx.x * 256 + threadIdx.x) * 4;
  if (i < n) {
    float4 v = *(const float4*)&src[i];
    uint2 o; o.x = pack2(v.x, v.y); o.y = pack2(v.z, v.w);
    *(uint2*)&dst[i] = o;
  }
}

__global__ __launch_bounds__(256) void trans_f2b(u16* __restrict__ dst, const float* __restrict__ src, int R, int C) {
  __shared__ u16 t[64][66];
  int r0 = blockIdx.y * 64, c0 = blockIdx.x * 64;
  #pragma unroll
  for (int it = 0; it < 16; ++it) {
    int idx = threadIdx.x + it * 256;
    int r = idx >> 6, c = idx & 63;
    t[c][r] = f2b(src[(size_t)(r0 + r) * C + c0 + c]);
  }
  __syncthreads();
  #pragma unroll
  for (int it = 0; it < 16; ++it) {
    int idx = threadIdx.x + it * 256;
    int r = idx >> 6, c = idx & 63;
    dst[(size_t)(c0 + r) * R + r0 + c] = t[r][c];
  }
}

// batched 64x64 bf16 transposes: k-chunk (gathered), hfw, dY, dH  (768 tiles)
__global__ __launch_bounds__(256) void trans4(
    const u16* __restrict__ kall, int chunk, u16* __restrict__ kcbt,
    const u16* __restrict__ hfw, u16* __restrict__ hfwt,
    const u16* __restrict__ dY,  u16* __restrict__ dYt,
    const u16* __restrict__ dH,  u16* __restrict__ dHt)
{
  int t = blockIdx.x;
  const u16* src; u16* dst; int C; int ti; bool gat = false;
  if (t < 128)      { src = kall; dst = kcbt; C = 1024; ti = t; gat = true; }
  else if (t < 384) { src = hfw;  dst = hfwt; C = 2048; ti = t - 128; }
  else if (t < 512) { src = dY;   dst = dYt;  C = 1024; ti = t - 384; }
  else              { src = dH;   dst = dHt;  C = 2048; ti = t - 512; }
  const int R = 512;
  int tpr = C >> 6;
  int r0 = (ti / tpr) * 64, c0 = (ti % tpr) * 64;
  size_t rowbase = gat ? ((size_t)(r0 >> 6) * SEQ + (size_t)chunk * CHUNKSZ) : (size_t)r0;
  __shared__ u16 tl[64][72];
  #pragma unroll
  for (int it = 0; it < 2; ++it) {
    int u = threadIdx.x + it * 256;
    int r = u >> 3, cg = (u & 7) * 8;
    uint4 v = *(const uint4*)&src[(rowbase + r) * C + c0 + cg];
    const u16* e = (const u16*)&v;
    #pragma unroll
    for (int k = 0; k < 8; ++k) tl[cg + k][r] = e[k];
  }
  __syncthreads();
  #pragma unroll
  for (int it = 0; it < 2; ++it) {
    int u = threadIdx.x + it * 256;
    int rr = u >> 3, gg = (u & 7) * 8;
    *(uint4*)&dst[(size_t)(c0 + rr) * R + r0 + gg] = *(uint4*)&tl[rr][gg];
  }
}

// ---------------------------------------------------------------------------
// small fused kernels
// ---------------------------------------------------------------------------
__global__ __launch_bounds__(256) void dots_kernel(
    const float* __restrict__ x, const float* __restrict__ aw,
    const float* __restrict__ tw, const float* __restrict__ ew,
    float* __restrict__ dA, float* __restrict__ dT, float* __restrict__ dE)
{
  int b = blockIdx.x >> 5, c = blockIdx.x & 31;
  const float* base = x + ((size_t)b * SEQ + (size_t)c * CHUNKSZ) * HD;
  float a = 0.f, t = 0.f, e = 0.f;
  for (int it = 0; it < 64; ++it) {
    int j = (it * 256 + threadIdx.x) * 4;
    float4 xv = *(const float4*)&base[j];
    float4 av = *(const float4*)&aw[j];
    float4 tv = *(const float4*)&tw[j];
    float4 ev = *(const float4*)&ew[j];
    a += xv.x * av.x + xv.y * av.y + xv.z * av.z + xv.w * av.w;
    t += xv.x * tv.x + xv.y * tv.y + xv.z * tv.z + xv.w * tv.w;
    e += xv.x * ev.x + xv.y * ev.y + xv.z * ev.z + xv.w * ev.w;
  }
  __shared__ float s4[4];
  a = block_reduce_sum(a, s4);
  t = block_reduce_sum(t, s4);
  e = block_reduce_sum(e, s4);
  if (threadIdx.x == 0) { dA[blockIdx.x] = a; dT[blockIdx.x] = t; dE[blockIdx.x] = e; }
}

__global__ __launch_bounds__(256) void coeff_kernel(
    const float* __restrict__ dA, const float* __restrict__ dT, const float* __restrict__ dE,
    float* __restrict__ betaA, float* __restrict__ etaA, float* __restrict__ thetaA)
{
  int t = threadIdx.x;
  if (t < 256) thetaA[t] = sigmoidf_(dT[t]) * 0.01f;
  if (t < 32) {
    float sa = 0.f, se = 0.f;
    for (int b = 0; b < NB; ++b) { sa += dA[b * 32 + t]; se += dE[b * 32 + t]; }
    betaA[t] = 1.f - sigmoidf_(sa / 8.f);
    etaA[t]  = sigmoidf_(se / 8.f);
  }
}

// dstb = f2b(rmsnorm(silu(src)) * nw); SRCB: src is bf16
template<bool SRCB>
__global__ __launch_bounds__(256) void post_norm(
    u16* __restrict__ dstb, const float* __restrict__ srcf,
    const u16* __restrict__ srcb, const float* __restrict__ nw)
{
  size_t off = (size_t)blockIdx.x * HD;
  float sv[4]; float ss = 0.f;
  #pragma unroll
  for (int i = 0; i < 4; ++i) {
    int j = i * 256 + threadIdx.x;
    float z = SRCB ? b2f(srcb[off + j]) : srcf[off + j];
    float s = siluf_(z);
    sv[i] = s; ss += s * s;
  }
  __shared__ float s4[4];
  ss = block_reduce_sum(ss, s4);
  float rs = rsqrtf(ss / (float)HD + EPSF);
  #pragma unroll
  for (int i = 0; i < 4; ++i) {
    int j = i * 256 + threadIdx.x;
    dstb[off + j] = f2b(sv[i] * rs * nw[j]);
  }
}

// per-row loss grad: k,v read as bf16 (gathered rows of k_all/v_all)
__global__ __launch_bounds__(256) void loss_grad(
    const float* __restrict__ y, const u16* __restrict__ kall, const u16* __restrict__ vall,
    const float* __restrict__ ln, const float* __restrict__ thetaA, int c,
    float* __restrict__ g, u16* __restrict__ dYbf, float* __restrict__ srow)
{
  int r = blockIdx.x;
  size_t off = (size_t)r * HD;
  size_t goff = (size_t)GATHER(r, c) * HD;
  float th = thetaA[(r >> 6) * 32 + c];
  float yv[4], lnv[4];
  float ss = 0.f;
  #pragma unroll
  for (int i = 0; i < 4; ++i) {
    int j = i * 256 + threadIdx.x;
    yv[i] = y[off + j];
    lnv[i] = ln[j];
    ss += yv[i] * yv[i];
  }
  __shared__ float s4[4];
  ss = block_reduce_sum(ss, s4);
  float s = rsqrtf(ss / (float)HD + EPSF);
  float coef = 2.f * th / MTOT;
  float gv[4]; float t = 0.f;
  #pragma unroll
  for (int i = 0; i < 4; ++i) {
    int j = i * 256 + threadIdx.x;
    float pred = b2f(kall[goff + j]) + yv[i] * s * lnv[i];
    float gg = coef * (pred - b2f(vall[goff + j]));
    gv[i] = gg;
    g[off + j] = gg;
    t += gg * lnv[i] * yv[i];
  }
  t = block_reduce_sum(t, s4);
  float c3 = s * s * s * t * (1.f / (float)HD);
  #pragma unroll
  for (int i = 0; i < 4; ++i) {
    int j = i * 256 + threadIdx.x;
    dYbf[off + j] = f2b(s * gv[i] * lnv[i] - c3 * yv[i]);
  }
  if (threadIdx.x == 0) srow[r] = s;
}

// Gln + fold ||Gln||^2 into nsq[c]
__global__ __launch_bounds__(256) void gln_kernel(
    const float* __restrict__ g, const float* __restrict__ y,
    const float* __restrict__ srow, float* __restrict__ Gln, float* __restrict__ nsqc)
{
  int j = blockIdx.x * 128 + (threadIdx.x & 127);
  int half = threadIdx.x >> 7;
  float acc = 0.f;
  for (int rr = 0; rr < 256; ++rr) {
    int r = half * 256 + rr;
    size_t o = (size_t)r * HD + j;
    acc += g[o] * y[o] * srow[r];
  }
  __shared__ float part[128];
  if (!half) part[threadIdx.x] = acc;
  __syncthreads();
  if (half) {
    float tot = acc + part[threadIdx.x - 128];
    Gln[j] = tot;
    float sq = tot * tot;
    #pragma unroll
    for (int off = 32; off > 0; off >>= 1) sq += __shfl_down(sq, off);
    if ((threadIdx.x & 63) == 0) atomicAdd(nsqc, sq);
  }
}

// merged update: blocks [0,512)=W1 tiles (+w1b,+w1tb), [512,1536)=W0 flat, 1536=ln
__global__ __launch_bounds__(256) void update_all(
    float* __restrict__ mw0, float* __restrict__ sw0, const float* __restrict__ g0, u16* __restrict__ w0b,
    float* __restrict__ mw1, float* __restrict__ sw1, const float* __restrict__ g1,
    u16* __restrict__ w1b, u16* __restrict__ w1tb,
    float* __restrict__ mln, float* __restrict__ sln, const float* __restrict__ gl,
    const float* __restrict__ etaA, const float* __restrict__ betaA, int c,
    const float* __restrict__ nsqc)
{
  float clip = fminf(1.0f / (sqrtf(*nsqc) + 1e-6f), 1.0f);
  float eta = etaA[c], beta = betaA[c];
  int bid = blockIdx.x;
  if (bid < 512) {
    int r0 = (bid >> 5) * 64, c0 = (bid & 31) * 64;
    __shared__ u16 tl[64][72];
    #pragma unroll
    for (int it = 0; it < 4; ++it) {
      int u = threadIdx.x + it * 256;
      int r = u >> 4, cg = (u & 15) * 4;
      size_t i = (size_t)(r0 + r) * ID + c0 + cg;
      float4 s = *(float4*)&sw1[i];
      float4 g = *(const float4*)&g1[i];
      float4 m = *(float4*)&mw1[i];
      s.x = eta * s.x - clip * g.x; m.x = beta * m.x + s.x;
      s.y = eta * s.y - clip * g.y; m.y = beta * m.y + s.y;
      s.z = eta * s.z - clip * g.z; m.z = beta * m.z + s.z;
      s.w = eta * s.w - clip * g.w; m.w = beta * m.w + s.w;
      *(float4*)&sw1[i] = s;
      *(float4*)&mw1[i] = m;
      u16 b0 = f2b(m.x), b1 = f2b(m.y), b2 = f2b(m.z), b3 = f2b(m.w);
      uint2 o; o.x = (u32)b0 | ((u32)b1 << 16); o.y = (u32)b2 | ((u32)b3 << 16);
      *(uint2*)&w1b[i] = o;
      tl[cg + 0][r] = b0; tl[cg + 1][r] = b1; tl[cg + 2][r] = b2; tl[cg + 3][r] = b3;
    }
    __syncthreads();
    #pragma unroll
    for (int it = 0; it < 2; ++it) {
      int u = threadIdx.x + it * 256;
      int rr = u >> 3, gg = (u & 7) * 8;
      *(uint4*)&w1tb[(size_t)(c0 + rr) * HD + r0 + gg] = *(uint4*)&tl[rr][gg];
    }
  } else if (bid < 1536) {
    size_t i0 = (size_t)(bid - 512) * 2048 + (size_t)threadIdx.x * 8;
    u16 bb[8];
    #pragma unroll
    for (int h = 0; h < 2; ++h) {
      size_t i = i0 + h * 4;
      float4 s = *(float4*)&sw0[i];
      float4 g = *(const float4*)&g0[i];
      float4 m = *(float4*)&mw0[i];
      s.x = eta * s.x - clip * g.x; m.x = beta * m.x + s.x;
      s.y = eta * s.y - clip * g.y; m.y = beta * m.y + s.y;
      s.z = eta * s.z - clip * g.z; m.z = beta * m.z + s.z;
      s.w = eta * s.w - clip * g.w; m.w = beta * m.w + s.w;
      *(float4*)&sw0[i] = s;
      *(float4*)&mw0[i] = m;
      bb[h * 4 + 0] = f2b(m.x); bb[h * 4 + 1] = f2b(m.y);
      bb[h * 4 + 2] = f2b(m.z); bb[h * 4 + 3] = f2b(m.w);
    }
    *(uint4*)&w0b[i0] = *(uint4*)bb;
  } else {
    int i = threadIdx.x * 4;
    #pragma unroll
    for (int k = 0; k < 4; ++k) {
      float ns = eta * sln[i + k] - clip * gl[i + k];
      sln[i + k] = ns;
      mln[i + k] = beta * mln[i + k] + ns;
    }
  }
}

// out = q + rmsnorm(y2)*ln, with q recomputed from zq (q = rmsnorm(silu(zq))*qn)
__global__ __launch_bounds__(256) void final_out_kernel(
    float* __restrict__ out, const float* __restrict__ zq, const float* __restrict__ y2,
    const float* __restrict__ qn, const float* __restrict__ ln)
{
  size_t off = (size_t)blockIdx.x * HD;
  float sv[4], yv[4];
  float ss1 = 0.f, ss2 = 0.f;
  #pragma unroll
  for (int i = 0; i < 4; ++i) {
    int j = i * 256 + threadIdx.x;
    float s = siluf_(zq[off + j]);
    sv[i] = s; ss1 += s * s;
    yv[i] = y2[off + j];
    ss2 += yv[i] * yv[i];
  }
  __shared__ float s4[4];
  ss1 = block_reduce_sum(ss1, s4);
  ss2 = block_reduce_sum(ss2, s4);
  float rs1 = rsqrtf(ss1 / (float)HD + EPSF);
  float rs2 = rsqrtf(ss2 / (float)HD + EPSF);
  #pragma unroll
  for (int i = 0; i < 4; ++i) {
    int j = i * 256 + threadIdx.x;
    out[off + j] = sv[i] * rs1 * qn[j] + yv[i] * rs2 * ln[j];
  }
}

// ---------------------------------------------------------------------------
// launch
// ---------------------------------------------------------------------------
extern "C" void kernel_launch(void* const* d_in, const int* in_sizes, int n_in,
                              void* d_out, int out_size, void* d_ws, size_t ws_size,
                              hipStream_t stream) {
  const float* x   = (const float*)d_in[0];
  const float* wq  = (const float*)d_in[1];
  const float* wk  = (const float*)d_in[2];
  const float* wv  = (const float*)d_in[3];
  const float* qn  = (const float*)d_in[4];
  const float* kn  = (const float*)d_in[5];
  const float* aw  = (const float*)d_in[6];
  const float* tw  = (const float*)d_in[7];
  const float* ew  = (const float*)d_in[8];
  const float* w0i = (const float*)d_in[9];
  const float* w1i = (const float*)d_in[10];
  const float* lni = (const float*)d_in[11];
  float* out = (float*)d_out;

  float* p = (float*)d_ws;
  auto alloc = [&](size_t n) { n = (n + 63) & ~(size_t)63; float* r = p; p += n; return r; };
  float* memW0  = alloc((size_t)ID * HD);
  float* memW1  = alloc((size_t)HD * ID);
  float* memLn  = alloc(HD);
  float* surpW0 = alloc((size_t)ID * HD);   // surpW0+surpW1 also: zk_all (setup), zq (retrieval)
  float* surpW1 = alloc((size_t)HD * ID);
  float* surpLn = alloc(HD);
  float* Gw0    = alloc((size_t)ID * HD);   // Gw0+Gw1 also: y2 (retrieval)
  float* Gw1    = alloc((size_t)HD * ID);
  float* Gln    = alloc(HD);
  float* zfw    = alloc((size_t)ROWS * ID); // zfw+ybuf+gbuf also: qb_bf (retrieval)
  float* ybuf   = alloc((size_t)ROWS * HD);
  float* gbuf   = alloc((size_t)ROWS * HD);
  float* srow   = alloc(ROWS);
  float* dotA   = alloc(256);
  float* dotT   = alloc(256);
  float* dotE   = alloc(256);
  float* betaA  = alloc(64);
  float* etaA   = alloc(64);
  float* thetaA = alloc(256);
  float* nsq    = alloc(64);

  u16* bp = (u16*)p;
  auto balloc = [&](size_t n) { n = (n + 63) & ~(size_t)63; u16* r = bp; bp += n; return r; };
  u16* wq_bf  = balloc((size_t)HD * HD);
  u16* wk_bf  = balloc((size_t)HD * HD);
  u16* wv_bf  = balloc((size_t)HD * HD);
  u16* W0_bf  = balloc((size_t)ID * HD);
  u16* W1_bf  = balloc((size_t)HD * ID);
  u16* W1t_bf = balloc((size_t)ID * HD);
  u16* k_all  = balloc((size_t)NB * SEQ * HD);  // also: h_bf (retrieval)
  u16* v_all  = balloc((size_t)NB * SEQ * HD);
  u16* hfw_bf = balloc((size_t)ROWS * ID);
  u16* hfwt   = balloc((size_t)ID * ROWS);
  u16* dY_bf  = balloc((size_t)ROWS * HD);
  u16* dYt    = balloc((size_t)HD * ROWS);
  u16* dH_bf  = balloc((size_t)ROWS * ID);
  u16* dHt    = balloc((size_t)ID * ROWS);
  u16* kcbt   = balloc((size_t)HD * ROWS);
  size_t needed = (size_t)((char*)bp - (char*)d_ws);
  if (needed > ws_size) return;

  u16* zk_all = (u16*)surpW0;  // 16.8M u16 fits in surpW0..Gw1 (33.5 MB); dead before memset

  // ---- setup ----
  conv_f2b<<<(HD * HD) / 1024, 256, 0, stream>>>(wq_bf, wq, HD * HD);
  conv_f2b<<<(HD * HD) / 1024, 256, 0, stream>>>(wk_bf, wk, HD * HD);
  conv_f2b<<<(HD * HD) / 1024, 256, 0, stream>>>(wv_bf, wv, HD * HD);
  conv_f2b<<<(ID * HD) / 1024, 256, 0, stream>>>(W0_bf, w0i, ID * HD);
  conv_f2b<<<(HD * ID) / 1024, 256, 0, stream>>>(W1_bf, w1i, HD * ID);
  trans_f2b<<<dim3(ID / 64, HD / 64), 256, 0, stream>>>(W1t_bf, w1i, HD, ID);
  dots_kernel<<<256, 256, 0, stream>>>(x, aw, tw, ew, dotA, dotT, dotE);
  coeff_kernel<<<1, 256, 0, stream>>>(dotA, dotT, dotE, betaA, etaA, thetaA);
  // batched k/v projections over all 16384 rows: z=0 -> zk_all (raw bf16), z=1 -> v_all (silu bf16)
  gemm128_t<2, true><<<dim3(HD / 128, (NB * SEQ) / 128, 2), 256, 0, stream>>>(
      nullptr, zk_all, v_all, nullptr, x, wk_bf, wv_bf, NB * SEQ, HD, HD);
  post_norm<true><<<NB * SEQ, 256, 0, stream>>>(k_all, nullptr, zk_all, kn);
  // state init (after zk_all is dead — it aliases surp/G)
  hipMemcpyAsync(memW0, w0i, (size_t)ID * HD * 4, hipMemcpyDeviceToDevice, stream);
  hipMemcpyAsync(memW1, w1i, (size_t)HD * ID * 4, hipMemcpyDeviceToDevice, stream);
  hipMemcpyAsync(memLn, lni, (size_t)HD * 4, hipMemcpyDeviceToDevice, stream);
  hipMemsetAsync(surpW0, 0, ((size_t)ID * HD * 2 + HD + 64) * 4, stream);
  hipMemsetAsync(nsq, 0, 64 * 4, stream);

  // ---- sequential scan (8 dispatches per chunk) ----
  for (int c = 0; c < NCHUNK; ++c) {
    gemm64_fwd<<<dim3(ID / 64, ROWS / 64), 256, 0, stream>>>(
        zfw, hfw_bf, k_all, W0_bf, ID, HD, c);
    gemm_y32<<<dim3(HD / 64, ROWS / 32), 128, 0, stream>>>(ybuf, hfw_bf, W1_bf, HD, ID);
    loss_grad<<<ROWS, 256, 0, stream>>>(ybuf, k_all, v_all, memLn, thetaA, c, gbuf, dY_bf, srow);
    gln_kernel<<<8, 256, 0, stream>>>(gbuf, ybuf, srow, Gln, nsq + c);
    gemm64_dh<<<dim3(ID / 64, ROWS / 64), 256, 0, stream>>>(
        dH_bf, dY_bf, W1t_bf, zfw, ID, HD);
    trans4<<<768, 256, 0, stream>>>(k_all, c, kcbt, hfw_bf, hfwt, dY_bf, dYt, dH_bf, dHt);
    gemm_grads<<<1024, 256, 0, stream>>>(Gw1, dYt, hfwt, Gw0, dHt, kcbt, nsq + c);
    update_all<<<1537, 256, 0, stream>>>(
        memW0, surpW0, Gw0, W0_bf, memW1, surpW1, Gw1, W1_bf, W1t_bf,
        memLn, surpLn, Gln, etaA, betaA, c, nsq + c);
  }

  // ---- retrieval: 4 blocks of 4096 rows; alias dead scan buffers ----
  const int RB = 4096;
  float* zq    = surpW0;        // 4M f32 (surpW0+surpW1)
  u16*   qb_bf = (u16*)zfw;     // 4M u16 (zfw+ybuf+gbuf)
  u16*   h_bf  = k_all;         // 8M u16 of k_all's 16M
  float* y2    = Gw0;           // 4M f32 (Gw0+Gw1)
  for (int blk = 0; blk < (NB * SEQ) / RB; ++blk) {
    const float* xb = x + (size_t)blk * RB * HD;
    gemm128_t<0, true><<<dim3(HD / 128, RB / 128), 256, 0, stream>>>(
        zq, nullptr, nullptr, nullptr, xb, wq_bf, nullptr, RB, HD, HD);
    post_norm<false><<<RB, 256, 0, stream>>>(qb_bf, zq, nullptr, qn);
    gemm128_t<1, false><<<dim3(ID / 128, RB / 128), 256, 0, stream>>>(
        nullptr, h_bf, nullptr, qb_bf, nullptr, W0_bf, nullptr, RB, ID, HD);
    gemm128_t<0, false><<<dim3(HD / 128, RB / 128), 256, 0, stream>>>(
        y2, nullptr, nullptr, h_bf, nullptr, W1_bf, nullptr, RB, HD, ID);
    final_out_kernel<<<RB, 256, 0, stream>>>(out + (size_t)blk * RB * HD, zq, y2, qn, memLn);
  }
}